// Round 11
// baseline (108.289 us; speedup 1.0000x reference)
//
#include <hip/hip_runtime.h>
#include <hip/hip_bf16.h>

#define TSEQ 1024
#define DMODEL 1024
#define NHEAD 16
#define NKV 4
#define HDIM 64
#define KVDIM 256   /* NKV*HDIM */
#define NBATCH 2

typedef __attribute__((ext_vector_type(4))) float f32x4;
typedef __attribute__((ext_vector_type(8))) short bf16x8;

// ---------- helpers ----------
__device__ __forceinline__ unsigned f2b_pack(float a, float b) {
    unsigned ua = __float_as_uint(a);
    ua = (ua + 0x7FFFu + ((ua >> 16) & 1u)) >> 16;
    unsigned ub = __float_as_uint(b);
    ub = (ub + 0x7FFFu + ((ub >> 16) & 1u)) & 0xFFFF0000u;
    return ua | ub;
}
__device__ __forceinline__ unsigned short f2b1(float x) {
    unsigned u = __float_as_uint(x);
    u = (u + 0x7FFFu + ((u >> 16) & 1u)) >> 16;
    return (unsigned short)u;
}
__device__ __forceinline__ float b2f(unsigned short u) {
    return __uint_as_float(((unsigned)u) << 16);
}
__device__ __forceinline__ void gload16(const void* g, void* l) {
    __builtin_amdgcn_global_load_lds(
        (const __attribute__((address_space(1))) void*)g,
        (__attribute__((address_space(3))) void*)l, 16, 0, 0);
}

// ---------- prep: rel f32->bf16 + 4 weight transposes (qkv converts now fused into GEMMs) ----------
__global__ __launch_bounds__(256) void prep(
    const float* __restrict__ rel,
    const float* __restrict__ Wq, const float* __restrict__ Wk,
    const float* __restrict__ Wv, const float* __restrict__ Wo,
    unsigned* __restrict__ relb,
    unsigned short* __restrict__ WqT, unsigned short* __restrict__ WkT,
    unsigned short* __restrict__ WvT, unsigned short* __restrict__ WoT)
{
    const int bid = blockIdx.x;
    if (bid < 4) {
        int i = bid * 256 + threadIdx.x;   // 1024 x uint4 = 8192 bf16
        const float4* s = (const float4*)(rel + (size_t)127 * 64 + (size_t)i * 8);
        float4 a = s[0], b = s[1];
        uint4 o = { f2b_pack(a.x, a.y), f2b_pack(a.z, a.w),
                    f2b_pack(b.x, b.y), f2b_pack(b.z, b.w) };
        ((uint4*)relb)[i] = o;
        return;
    }
    const float* W; unsigned short* WT; int N, l;
    if (bid < 1028)      { W = Wq; WT = WqT; N = 1024; l = bid - 4; }
    else if (bid < 1284) { W = Wk; WT = WkT; N = 256;  l = bid - 1028; }
    else if (bid < 1540) { W = Wv; WT = WvT; N = 256;  l = bid - 1284; }
    else                 { W = Wo; WT = WoT; N = 1024; l = bid - 1540; }
    const int nbx = N >> 5;
    const int n0 = (l % nbx) * 32, k0 = (l / nbx) * 32;
    __shared__ float t[32][33];
    const int tx = threadIdx.x & 31, ty = threadIdx.x >> 5;
    #pragma unroll
    for (int i = 0; i < 4; i++)
        t[ty + i * 8][tx] = W[(size_t)(k0 + ty + i * 8) * N + n0 + tx];
    __syncthreads();
    #pragma unroll
    for (int i = 0; i < 4; i++)
        WT[(size_t)(n0 + ty + i * 8) * 1024 + k0 + tx] = f2b1(t[tx][ty + i * 8]);
}

// ---------- bf16 MFMA GEMM body (bf16 A): C = alpha * A[M,K] @ BT[N,K]^T ----------
template<bool OUTBF16>
__device__ __forceinline__ void gemm_body(
    const unsigned short* __restrict__ A, const unsigned short* __restrict__ BT,
    void* __restrict__ Cv, int M, int N, int K, float alpha)
{
    __shared__ __attribute__((aligned(16))) unsigned short As[64 * 64];
    __shared__ __attribute__((aligned(16))) unsigned short Bs[64 * 64];
    const int tid = threadIdx.x;
    const int lane = tid & 63, wave = tid >> 6;
    const int wr = wave >> 1, wc = wave & 1;
    const int m0 = blockIdx.y * 64, n0 = blockIdx.x * 64;
    const int qn = lane & 15, lg8 = (lane >> 4) * 8;
    const int rsub = lane >> 3, cb8 = (lane & 7) * 8;

    const unsigned short* aSrc = A + (size_t)(m0 + wave * 16 + rsub) * K + cb8;
    const unsigned short* bSrc = BT + (size_t)(n0 + wave * 16 + rsub) * K + cb8;

    f32x4 acc[2][2];
    #pragma unroll
    for (int x = 0; x < 2; x++)
        #pragma unroll
        for (int y = 0; y < 2; y++)
            acc[x][y] = (f32x4){0.f, 0.f, 0.f, 0.f};

    for (int k0 = 0; k0 < K; k0 += 64) {
        #pragma unroll
        for (int i = 0; i < 2; i++)
            gload16(aSrc + (size_t)i * 8 * K + k0, &As[(wave * 2 + i) * 512]);
        #pragma unroll
        for (int i = 0; i < 2; i++)
            gload16(bSrc + (size_t)i * 8 * K + k0, &Bs[(wave * 2 + i) * 512]);
        __syncthreads();
        #pragma unroll
        for (int ks = 0; ks < 2; ks++) {
            bf16x8 af[2], bfr[2];
            #pragma unroll
            for (int x = 0; x < 2; x++)
                af[x] = *(const bf16x8*)&As[(wr * 32 + x * 16 + qn) * 64 + ks * 32 + lg8];
            #pragma unroll
            for (int y = 0; y < 2; y++)
                bfr[y] = *(const bf16x8*)&Bs[(wc * 32 + y * 16 + qn) * 64 + ks * 32 + lg8];
            #pragma unroll
            for (int x = 0; x < 2; x++)
                #pragma unroll
                for (int y = 0; y < 2; y++)
                    acc[x][y] = __builtin_amdgcn_mfma_f32_16x16x32_bf16(af[x], bfr[y], acc[x][y], 0, 0, 0);
        }
        __syncthreads();
    }
    const int r4 = (lane >> 4) * 4;
    #pragma unroll
    for (int x = 0; x < 2; x++)
        #pragma unroll
        for (int y = 0; y < 2; y++) {
            const int row = m0 + wr * 32 + x * 16 + r4;
            const int col = n0 + wc * 32 + y * 16 + qn;
            #pragma unroll
            for (int r = 0; r < 4; r++) {
                float vv = acc[x][y][r] * alpha;
                if (OUTBF16)
                    ((unsigned short*)Cv)[(size_t)(row + r) * N + col] = f2b1(vv);
                else
                    ((float*)Cv)[(size_t)(row + r) * N + col] = vv;
            }
        }
}

template<bool OUTBF16>
__global__ __launch_bounds__(256) void gemm_bt(
    const unsigned short* __restrict__ A, const unsigned short* __restrict__ BT,
    void* __restrict__ Cv, int M, int N, int K, float alpha)
{
    gemm_body<OUTBF16>(A, BT, Cv, M, N, K, alpha);
}

// ---------- GEMM body with FUSED f32->bf16 A-staging: C = alpha * bf16(A_f32) @ BT^T ----------
__device__ __forceinline__ void gemm_a32_body(
    const float* __restrict__ A, const unsigned short* __restrict__ BT,
    unsigned short* __restrict__ C, int M, int N, int K, float alpha)
{
    __shared__ __attribute__((aligned(16))) unsigned short As[64 * 64];
    __shared__ __attribute__((aligned(16))) unsigned short Bs[64 * 64];
    const int tid = threadIdx.x;
    const int lane = tid & 63, wave = tid >> 6;
    const int wr = wave >> 1, wc = wave & 1;
    const int m0 = blockIdx.y * 64, n0 = blockIdx.x * 64;
    const int qn = lane & 15, lg8 = (lane >> 4) * 8;
    const int rsub = lane >> 3, cb8 = (lane & 7) * 8;

    // A staging (f32 -> bf16): thread -> row tid>>2, f32 cols (tid&3)*16..+15
    const int arow = tid >> 2;
    const int ac0  = (tid & 3) << 4;
    const float* aSrc = A + (size_t)(m0 + arow) * K + ac0;
    const unsigned short* bSrc = BT + (size_t)(n0 + wave * 16 + rsub) * K + cb8;

    f32x4 acc[2][2];
    #pragma unroll
    for (int x = 0; x < 2; x++)
        #pragma unroll
        for (int y = 0; y < 2; y++)
            acc[x][y] = (f32x4){0.f, 0.f, 0.f, 0.f};

    for (int k0 = 0; k0 < K; k0 += 64) {
        // B async staging first (stays in flight during A convert)
        #pragma unroll
        for (int i = 0; i < 2; i++)
            gload16(bSrc + (size_t)i * 8 * K + k0, &Bs[(wave * 2 + i) * 512]);
        // A: 16 f32 loads + RNE pack + 2x ds_write_b128
        float4 a0 = *(const float4*)(aSrc + k0);
        float4 a1 = *(const float4*)(aSrc + k0 + 4);
        float4 a2 = *(const float4*)(aSrc + k0 + 8);
        float4 a3 = *(const float4*)(aSrc + k0 + 12);
        uint4 w0 = { f2b_pack(a0.x, a0.y), f2b_pack(a0.z, a0.w),
                     f2b_pack(a1.x, a1.y), f2b_pack(a1.z, a1.w) };
        uint4 w1 = { f2b_pack(a2.x, a2.y), f2b_pack(a2.z, a2.w),
                     f2b_pack(a3.x, a3.y), f2b_pack(a3.z, a3.w) };
        *(uint4*)&As[arow * 64 + ac0]     = w0;
        *(uint4*)&As[arow * 64 + ac0 + 8] = w1;
        __syncthreads();
        #pragma unroll
        for (int ks = 0; ks < 2; ks++) {
            bf16x8 af[2], bfr[2];
            #pragma unroll
            for (int x = 0; x < 2; x++)
                af[x] = *(const bf16x8*)&As[(wr * 32 + x * 16 + qn) * 64 + ks * 32 + lg8];
            #pragma unroll
            for (int y = 0; y < 2; y++)
                bfr[y] = *(const bf16x8*)&Bs[(wc * 32 + y * 16 + qn) * 64 + ks * 32 + lg8];
            #pragma unroll
            for (int x = 0; x < 2; x++)
                #pragma unroll
                for (int y = 0; y < 2; y++)
                    acc[x][y] = __builtin_amdgcn_mfma_f32_16x16x32_bf16(af[x], bfr[y], acc[x][y], 0, 0, 0);
        }
        __syncthreads();
    }
    const int r4 = (lane >> 4) * 4;
    #pragma unroll
    for (int x = 0; x < 2; x++)
        #pragma unroll
        for (int y = 0; y < 2; y++) {
            const int row = m0 + wr * 32 + x * 16 + r4;
            const int col = n0 + wc * 32 + y * 16 + qn;
            #pragma unroll
            for (int r = 0; r < 4; r++)
                C[(size_t)(row + r) * N + col] = f2b1(acc[x][y][r] * alpha);
        }
}

__global__ __launch_bounds__(256) void gemm_a32(
    const float* __restrict__ A, const unsigned short* __restrict__ BT,
    unsigned short* __restrict__ C, int M, int N, int K, float alpha)
{
    gemm_a32_body(A, BT, C, M, N, K, alpha);
}

// K and V projections merged via blockIdx.z (fused-convert A path)
__global__ __launch_bounds__(256) void gemm_kv32(
    const float* __restrict__ k, const unsigned short* __restrict__ WkT,
    unsigned short* __restrict__ kh,
    const float* __restrict__ v, const unsigned short* __restrict__ WvT,
    unsigned short* __restrict__ vh)
{
    const float* A = blockIdx.z ? v : k;
    const unsigned short* B = blockIdx.z ? WvT : WkT;
    unsigned short* C = blockIdx.z ? vh : kh;
    gemm_a32_body(A, B, C, 2048, 256, 1024, 1.0f);
}

// ---------- MFMA flash attention, KVBLK=64 (round-5 verified kernel, verbatim) ----------
#define K_OFF(buf)  ((buf) * 8192)                    /* [64k][64d] bf16, XOR-swizzled rows */
#define V_OFF(buf)  (16384 + (buf) * 9216)            /* V^T: [64d][32 kpair dword], stride 36 dw */
#define P_OFF(w)    (34816 + (w) * 2176)              /* per-wave P^T: [32 kpair][16 q], stride 17 dw */
#define LDS_BYTES   43520

__global__ __launch_bounds__(256, 3) void attn_mfma(
    const unsigned short* __restrict__ qh, const unsigned short* __restrict__ kh,
    const unsigned short* __restrict__ vh, const unsigned short* __restrict__ rb,
    unsigned short* __restrict__ ctx)
{
    __shared__ __align__(16) unsigned char lds[LDS_BYTES];
    const int tid  = threadIdx.x;
    const int lane = tid & 63;
    const int wave = tid >> 6;
    const int qn   = lane & 15;
    const int lg   = lane >> 4;
    const int bh = blockIdx.y;
    const int b = bh >> 4, h = bh & 15;
    const int g = h >> 2;
    const int qt = 15 - (int)blockIdx.x;        // heavy q-tiles first
    const int qw0 = qt * 64 + wave * 16;
    const int qg  = qw0 + qn;
    const int nch = qt + 1;                     // 64-key chunks

    const unsigned short* kbase = kh + (size_t)b * TSEQ * KVDIM + g * HDIM;
    const unsigned short* vbase = vh + (size_t)b * TSEQ * KVDIM + g * HDIM;

    // Q fragments: col q=qn, rows d = dh*32 + lg*8 + i
    bf16x8 qf[2];
    {
        const unsigned short* qp = qh + (size_t)(b * TSEQ + qg) * DMODEL + h * HDIM;
        qf[0] = *(const bf16x8*)(qp + lg * 8);
        qf[1] = *(const bf16x8*)(qp + 32 + lg * 8);
    }
    const unsigned short* rbbase = rb + ((size_t)(b * TSEQ + qg) * NHEAD + h) * 128;
    const float cb = b2f(rbbase[127]);

    // staging thread mapping (64 keys)
    const int sk  = tid >> 2;            // K row 0..63
    const int sd0 = (tid & 3) << 4;      // K d-start elems (0,16,32,48), 2x bf16x8 each
    const int vkp = tid >> 3;            // V kpair 0..31
    const int vd0 = (tid & 7) << 3;      // V d-start elems (0,8,..,56), 8 dwords each

    f32x4 oa0 = {0.f,0.f,0.f,0.f}, oa1 = oa0, oa2 = oa0, oa3 = oa0;
    float mReg = -1e30f, lReg = 0.f;

    // ---- prologue: stage chunk 0 ----
    {
        bf16x8 kx0 = *(const bf16x8*)(kbase + (size_t)sk * KVDIM + sd0);
        bf16x8 kx1 = *(const bf16x8*)(kbase + (size_t)sk * KVDIM + sd0 + 8);
        uint4 va = *(const uint4*)(vbase + (size_t)(2 * vkp) * KVDIM + vd0);
        uint4 vvb = *(const uint4*)(vbase + (size_t)(2 * vkp + 1) * KVDIM + vd0);
        unsigned char* kd = lds + K_OFF(0) + sk * 128;
        const int sw = (sk & 7) << 4;
        *(bf16x8*)(kd + ((sd0 * 2) ^ sw)) = kx0;
        *(bf16x8*)(kd + ((sd0 * 2 + 16) ^ sw)) = kx1;
        unsigned char* vd = lds + V_OFF(0);
        const unsigned* ua = (const unsigned*)&va;
        const unsigned* ub = (const unsigned*)&vvb;
        #pragma unroll
        for (int j = 0; j < 8; j++) {
            unsigned lo = (ua[j >> 1] >> ((j & 1) * 16)) & 0xFFFFu;
            unsigned hi = (ub[j >> 1] >> ((j & 1) * 16)) & 0xFFFFu;
            *(unsigned*)(vd + (((vd0 + j) * 36 + vkp) * 4)) = lo | (hi << 16);
        }
    }
    __syncthreads();

    for (int c = 0; c < nch; c++) {
        const unsigned char* kbuf = lds + K_OFF(c & 1);
        const unsigned char* vbuf = lds + V_OFF(c & 1);
        // T14: issue next-chunk global loads early
        bf16x8 kx0, kx1; uint4 va, vvb;
        const bool stage = (c + 1 < nch);
        if (stage) {
            const int k0n = (c + 1) * 64;
            kx0 = *(const bf16x8*)(kbase + (size_t)(k0n + sk) * KVDIM + sd0);
            kx1 = *(const bf16x8*)(kbase + (size_t)(k0n + sk) * KVDIM + sd0 + 8);
            va  = *(const uint4*)(vbase + (size_t)(k0n + 2 * vkp) * KVDIM + vd0);
            vvb = *(const uint4*)(vbase + (size_t)(k0n + 2 * vkp + 1) * KVDIM + vd0);
        }
        {
            const int k0 = c * 64;
            float sa[4][4];
            const bool far = (qw0 - k0) >= 190;
            #pragma unroll
            for (int kt = 0; kt < 4; kt++)
                #pragma unroll
                for (int r = 0; r < 4; r++) {
                    if (far) { sa[kt][r] = cb; }
                    else {
                        int dist = qg - (k0 + kt * 16 + lg * 4 + r);
                        sa[kt][r] = (dist < 0) ? -1e30f : b2f(rbbase[min(dist, 127)]);
                    }
                }
            f32x4 acc[4];
            #pragma unroll
            for (int kt = 0; kt < 4; kt++)
                acc[kt] = (f32x4){sa[kt][0], sa[kt][1], sa[kt][2], sa[kt][3]};
            #pragma unroll
            for (int dh = 0; dh < 2; dh++) {
                #pragma unroll
                for (int kt = 0; kt < 4; kt++) {
                    const int kr = kt * 16 + qn;
                    bf16x8 kf = *(const bf16x8*)(kbuf + kr * 128 + ((dh * 64 + lg * 16) ^ ((kr & 7) << 4)));
                    acc[kt] = __builtin_amdgcn_mfma_f32_16x16x32_bf16(kf, qf[dh], acc[kt], 0, 0, 0);
                }
            }
            #pragma unroll
            for (int kt = 0; kt < 4; kt++) {
                sa[kt][0] = acc[kt][0]; sa[kt][1] = acc[kt][1];
                sa[kt][2] = acc[kt][2]; sa[kt][3] = acc[kt][3];
            }
            float mt = -1e30f;
            #pragma unroll
            for (int kt = 0; kt < 4; kt++)
                mt = fmaxf(mt, fmaxf(fmaxf(sa[kt][0], sa[kt][1]), fmaxf(sa[kt][2], sa[kt][3])));
            mt = fmaxf(mt, __shfl_xor(mt, 16));
            mt = fmaxf(mt, __shfl_xor(mt, 32));
            if (!__all(mt <= mReg + 8.0f)) {       // defer-max (T13)
                float mn = fmaxf(mReg, mt);
                float sc = __expf(mReg - mn);
                lReg *= sc;
                oa0 *= sc; oa1 *= sc; oa2 *= sc; oa3 *= sc;
                mReg = mn;
            }
            float ls = 0.f;
            #pragma unroll
            for (int kt = 0; kt < 4; kt++)
                #pragma unroll
                for (int r = 0; r < 4; r++) {
                    float e = __expf(sa[kt][r] - mReg);   // masked -> exp(-1e30)=0
                    sa[kt][r] = e; ls += e;
                }
            ls += __shfl_xor(ls, 16);
            ls += __shfl_xor(ls, 32);
            lReg += ls;
            // P^T -> per-wave LDS, read back as B-frags
            unsigned char* pb = lds + P_OFF(wave);
            #pragma unroll
            for (int kt = 0; kt < 4; kt++)
                #pragma unroll
                for (int i = 0; i < 2; i++) {
                    unsigned dw = f2b_pack(sa[kt][2 * i], sa[kt][2 * i + 1]);
                    *(unsigned*)(pb + ((kt * 8 + lg * 2 + i) * 17 + qn) * 4) = dw;
                }
            asm volatile("s_waitcnt lgkmcnt(0)" ::: "memory");
            __builtin_amdgcn_sched_barrier(0);                  // rule #18
            union { unsigned u[4]; bf16x8 v; } pf[2];
            #pragma unroll
            for (int ks = 0; ks < 2; ks++)
                #pragma unroll
                for (int j = 0; j < 4; j++)
                    pf[ks].u[j] = *(const unsigned*)(pb + (((ks * 16 + lg * 4 + j) * 17 + qn) * 4));
            #pragma unroll
            for (int ks = 0; ks < 2; ks++) {
                bf16x8 vf0 = *(const bf16x8*)(vbuf + (((0 * 16 + qn) * 36 + ks * 16 + lg * 4) * 4));
                oa0 = __builtin_amdgcn_mfma_f32_16x16x32_bf16(vf0, pf[ks].v, oa0, 0, 0, 0);
                bf16x8 vf1 = *(const bf16x8*)(vbuf + (((1 * 16 + qn) * 36 + ks * 16 + lg * 4) * 4));
                oa1 = __builtin_amdgcn_mfma_f32_16x16x32_bf16(vf1, pf[ks].v, oa1, 0, 0, 0);
                bf16x8 vf2 = *(const bf16x8*)(vbuf + (((2 * 16 + qn) * 36 + ks * 16 + lg * 4) * 4));
                oa2 = __builtin_amdgcn_mfma_f32_16x16x32_bf16(vf2, pf[ks].v, oa2, 0, 0, 0);
                bf16x8 vf3 = *(const bf16x8*)(vbuf + (((3 * 16 + qn) * 36 + ks * 16 + lg * 4) * 4));
                oa3 = __builtin_amdgcn_mfma_f32_16x16x32_bf16(vf3, pf[ks].v, oa3, 0, 0, 0);
            }
        }
        if (stage) {
            unsigned char* kd = lds + K_OFF((c + 1) & 1) + sk * 128;
            const int sw = (sk & 7) << 4;
            *(bf16x8*)(kd + ((sd0 * 2) ^ sw)) = kx0;
            *(bf16x8*)(kd + ((sd0 * 2 + 16) ^ sw)) = kx1;
            unsigned char* vd = lds + V_OFF((c + 1) & 1);
            const unsigned* ua = (const unsigned*)&va;
            const unsigned* ub = (const unsigned*)&vvb;
            #pragma unroll
            for (int j = 0; j < 8; j++) {
                unsigned lo = (ua[j >> 1] >> ((j & 1) * 16)) & 0xFFFFu;
                unsigned hi = (ub[j >> 1] >> ((j & 1) * 16)) & 0xFFFFu;
                *(unsigned*)(vd + (((vd0 + j) * 36 + vkp) * 4)) = lo | (hi << 16);
            }
        }
        __syncthreads();
    }

    // epilogue: O^T rows d = dt*16 + lg*4 + r, col q = qn -> bf16 ctx
    const float iL = 1.0f / lReg;
    unsigned short* op = ctx + (size_t)(b * TSEQ + qg) * DMODEL + h * HDIM;
    uint2 s;
    s.x = f2b_pack(oa0[0] * iL, oa0[1] * iL); s.y = f2b_pack(oa0[2] * iL, oa0[3] * iL);
    *(uint2*)(op + 0 * 16 + lg * 4) = s;
    s.x = f2b_pack(oa1[0] * iL, oa1[1] * iL); s.y = f2b_pack(oa1[2] * iL, oa1[3] * iL);
    *(uint2*)(op + 1 * 16 + lg * 4) = s;
    s.x = f2b_pack(oa2[0] * iL, oa2[1] * iL); s.y = f2b_pack(oa2[2] * iL, oa2[3] * iL);
    *(uint2*)(op + 2 * 16 + lg * 4) = s;
    s.x = f2b_pack(oa3[0] * iL, oa3[1] * iL); s.y = f2b_pack(oa3[2] * iL, oa3[3] * iL);
    *(uint2*)(op + 3 * 16 + lg * 4) = s;
}

extern "C" void kernel_launch(void* const* d_in, const int* in_sizes, int n_in,
                              void* d_out, int out_size, void* d_ws, size_t ws_size,
                              hipStream_t stream) {
    const float* q   = (const float*)d_in[0];
    const float* k   = (const float*)d_in[1];
    const float* v   = (const float*)d_in[2];
    const float* Wq  = (const float*)d_in[3];
    const float* Wk  = (const float*)d_in[4];
    const float* Wv  = (const float*)d_in[5];
    const float* Wo  = (const float*)d_in[6];
    const float* rel = (const float*)d_in[7];
    // d_in[8] = attn_mask: exactly causal (triu k=1) -> computed analytically.
    float* out = (float*)d_out;

    // workspace (ushort units), ~23 MB
    unsigned short* WqT  = (unsigned short*)d_ws;              // 1M
    unsigned short* WkT  = WqT  + (size_t)1024 * 1024;         // 256K
    unsigned short* WvT  = WkT  + (size_t)256 * 1024;          // 256K
    unsigned short* WoT  = WvT  + (size_t)256 * 1024;          // 1M
    unsigned short* relb = WoT  + (size_t)1024 * 1024;         // 8K
    unsigned short* qh   = relb + 8192;                        // 2M
    unsigned short* kh   = qh   + (size_t)2048 * 1024;         // 512K
    unsigned short* vh   = kh   + (size_t)2048 * 256;          // 512K
    unsigned short* rbb  = vh   + (size_t)2048 * 256;          // 4M
    unsigned short* ctx  = rbb  + (size_t)32768 * 128;         // 2M

    prep<<<2564, 256, 0, stream>>>(rel, Wq, Wk, Wv, Wo,
                                   (unsigned*)relb, WqT, WkT, WvT, WoT);
    // projections with fused f32->bf16 A conversion
    gemm_a32<<<dim3(16, 32), 256, 0, stream>>>(q, WqT, qh, 2048, 1024, 1024, 0.125f);
    gemm_kv32<<<dim3(4, 32, 2), 256, 0, stream>>>(k, WkT, kh, v, WvT, vh);
    // rb[(b,t,h)][j] = qh_row(64) . rel[127+j]   [32768,128] = [32768,64]@[128,64]^T
    gemm_bt<true><<<dim3(2, 512), 256, 0, stream>>>(qh, relb, rbb, 32768, 128, 64, 1.0f);
    attn_mfma<<<dim3(16, 32), 256, 0, stream>>>(qh, kh, vh, rbb, ctx);
    gemm_bt<false><<<dim3(16, 32), 256, 0, stream>>>(ctx, WoT, out, 2048, 1024, 1024, 1.0f);
}

// Round 12
// 107.458 us; speedup vs baseline: 1.0077x; 1.0077x over previous
//
#include <hip/hip_runtime.h>
#include <hip/hip_bf16.h>

#define TSEQ 1024
#define DMODEL 1024
#define NHEAD 16
#define NKV 4
#define HDIM 64
#define KVDIM 256   /* NKV*HDIM */
#define NBATCH 2

typedef __attribute__((ext_vector_type(4))) float f32x4;
typedef __attribute__((ext_vector_type(8))) short bf16x8;

// ---------- helpers ----------
__device__ __forceinline__ unsigned f2b_pack(float a, float b) {
    unsigned ua = __float_as_uint(a);
    ua = (ua + 0x7FFFu + ((ua >> 16) & 1u)) >> 16;
    unsigned ub = __float_as_uint(b);
    ub = (ub + 0x7FFFu + ((ub >> 16) & 1u)) & 0xFFFF0000u;
    return ua | ub;
}
__device__ __forceinline__ unsigned short f2b1(float x) {
    unsigned u = __float_as_uint(x);
    u = (u + 0x7FFFu + ((u >> 16) & 1u)) >> 16;
    return (unsigned short)u;
}
__device__ __forceinline__ float b2f(unsigned short u) {
    return __uint_as_float(((unsigned)u) << 16);
}
__device__ __forceinline__ void gload16(const void* g, void* l) {
    __builtin_amdgcn_global_load_lds(
        (const __attribute__((address_space(1))) void*)g,
        (__attribute__((address_space(3))) void*)l, 16, 0, 0);
}

// ---------- fused prep: q/k/v/rel f32->bf16 converts + 4 weight transposes ----------
__global__ __launch_bounds__(256) void prep(
    const float* __restrict__ q, const float* __restrict__ k,
    const float* __restrict__ v, const float* __restrict__ rel,
    const float* __restrict__ Wq, const float* __restrict__ Wk,
    const float* __restrict__ Wv, const float* __restrict__ Wo,
    unsigned* __restrict__ qb, unsigned* __restrict__ kb,
    unsigned* __restrict__ vb, unsigned* __restrict__ relb,
    unsigned short* __restrict__ WqT, unsigned short* __restrict__ WkT,
    unsigned short* __restrict__ WvT, unsigned short* __restrict__ WoT)
{
    const int bid = blockIdx.x;
    if (bid < 3072) {
        const float* src = bid < 1024 ? q : (bid < 2048 ? k : v);
        unsigned* dst = bid < 1024 ? qb : (bid < 2048 ? kb : vb);
        int i = (bid & 1023) * 256 + threadIdx.x;
        const float4* s = (const float4*)(src + (size_t)i * 8);
        float4 a = s[0], b = s[1];
        uint4 o = { f2b_pack(a.x, a.y), f2b_pack(a.z, a.w),
                    f2b_pack(b.x, b.y), f2b_pack(b.z, b.w) };
        ((uint4*)dst)[i] = o;
        return;
    }
    if (bid < 3076) {
        int i = (bid - 3072) * 256 + threadIdx.x;
        const float4* s = (const float4*)(rel + (size_t)127 * 64 + (size_t)i * 8);
        float4 a = s[0], b = s[1];
        uint4 o = { f2b_pack(a.x, a.y), f2b_pack(a.z, a.w),
                    f2b_pack(b.x, b.y), f2b_pack(b.z, b.w) };
        ((uint4*)relb)[i] = o;
        return;
    }
    const float* W; unsigned short* WT; int N, l;
    if (bid < 4100)      { W = Wq; WT = WqT; N = 1024; l = bid - 3076; }
    else if (bid < 4356) { W = Wk; WT = WkT; N = 256;  l = bid - 4100; }
    else if (bid < 4612) { W = Wv; WT = WvT; N = 256;  l = bid - 4356; }
    else                 { W = Wo; WT = WoT; N = 1024; l = bid - 4612; }
    const int nbx = N >> 5;
    const int n0 = (l % nbx) * 32, k0 = (l / nbx) * 32;
    __shared__ float t[32][33];
    const int tx = threadIdx.x & 31, ty = threadIdx.x >> 5;
    #pragma unroll
    for (int i = 0; i < 4; i++)
        t[ty + i * 8][tx] = W[(size_t)(k0 + ty + i * 8) * N + n0 + tx];
    __syncthreads();
    #pragma unroll
    for (int i = 0; i < 4; i++)
        WT[(size_t)(n0 + ty + i * 8) * 1024 + k0 + tx] = f2b1(t[tx][ty + i * 8]);
}

// ---------- bf16 MFMA GEMM body: C[M,N] = alpha * A[M,K] @ BT[N,K]^T ----------
template<bool OUTBF16>
__device__ __forceinline__ void gemm_body(
    const unsigned short* __restrict__ A, const unsigned short* __restrict__ BT,
    void* __restrict__ Cv, int M, int N, int K, float alpha)
{
    __shared__ __attribute__((aligned(16))) unsigned short As[64 * 64];
    __shared__ __attribute__((aligned(16))) unsigned short Bs[64 * 64];
    const int tid = threadIdx.x;
    const int lane = tid & 63, wave = tid >> 6;
    const int wr = wave >> 1, wc = wave & 1;
    const int m0 = blockIdx.y * 64, n0 = blockIdx.x * 64;
    const int qn = lane & 15, lg8 = (lane >> 4) * 8;
    const int rsub = lane >> 3, cb8 = (lane & 7) * 8;

    const unsigned short* aSrc = A + (size_t)(m0 + wave * 16 + rsub) * K + cb8;
    const unsigned short* bSrc = BT + (size_t)(n0 + wave * 16 + rsub) * K + cb8;

    f32x4 acc[2][2];
    #pragma unroll
    for (int x = 0; x < 2; x++)
        #pragma unroll
        for (int y = 0; y < 2; y++)
            acc[x][y] = (f32x4){0.f, 0.f, 0.f, 0.f};

    for (int k0 = 0; k0 < K; k0 += 64) {
        #pragma unroll
        for (int i = 0; i < 2; i++)
            gload16(aSrc + (size_t)i * 8 * K + k0, &As[(wave * 2 + i) * 512]);
        #pragma unroll
        for (int i = 0; i < 2; i++)
            gload16(bSrc + (size_t)i * 8 * K + k0, &Bs[(wave * 2 + i) * 512]);
        __syncthreads();
        #pragma unroll
        for (int ks = 0; ks < 2; ks++) {
            bf16x8 af[2], bfr[2];
            #pragma unroll
            for (int x = 0; x < 2; x++)
                af[x] = *(const bf16x8*)&As[(wr * 32 + x * 16 + qn) * 64 + ks * 32 + lg8];
            #pragma unroll
            for (int y = 0; y < 2; y++)
                bfr[y] = *(const bf16x8*)&Bs[(wc * 32 + y * 16 + qn) * 64 + ks * 32 + lg8];
            #pragma unroll
            for (int x = 0; x < 2; x++)
                #pragma unroll
                for (int y = 0; y < 2; y++)
                    acc[x][y] = __builtin_amdgcn_mfma_f32_16x16x32_bf16(af[x], bfr[y], acc[x][y], 0, 0, 0);
        }
        __syncthreads();
    }
    const int r4 = (lane >> 4) * 4;
    #pragma unroll
    for (int x = 0; x < 2; x++)
        #pragma unroll
        for (int y = 0; y < 2; y++) {
            const int row = m0 + wr * 32 + x * 16 + r4;
            const int col = n0 + wc * 32 + y * 16 + qn;
            #pragma unroll
            for (int r = 0; r < 4; r++) {
                float vv = acc[x][y][r] * alpha;
                if (OUTBF16)
                    ((unsigned short*)Cv)[(size_t)(row + r) * N + col] = f2b1(vv);
                else
                    ((float*)Cv)[(size_t)(row + r) * N + col] = vv;
            }
        }
}

template<bool OUTBF16>
__global__ __launch_bounds__(256) void gemm_bt(
    const unsigned short* __restrict__ A, const unsigned short* __restrict__ BT,
    void* __restrict__ Cv, int M, int N, int K, float alpha)
{
    gemm_body<OUTBF16>(A, BT, Cv, M, N, K, alpha);
}

__global__ __launch_bounds__(256) void gemm_kv(
    const unsigned short* __restrict__ kb, const unsigned short* __restrict__ WkT,
    unsigned short* __restrict__ kh,
    const unsigned short* __restrict__ vb, const unsigned short* __restrict__ WvT,
    unsigned short* __restrict__ vh)
{
    const unsigned short* A = blockIdx.z ? vb : kb;
    const unsigned short* B = blockIdx.z ? WvT : WkT;
    unsigned short* C = blockIdx.z ? vh : kh;
    gemm_body<true>(A, B, C, 2048, 256, 1024, 1.0f);
}

// ---------- MFMA flash attention, KVBLK=64 (round-5 kernel; P-path now in-register) ----------
// P redistribution: lane (qn,lg) holds kpair D[kt][i] = kt*8+lg*2+i; PV B-frag
// needs kpair ks*16+lg*4+j. Pure lane-group permutation over {id,^16,^32,^48}:
//   s16 = lg<2 ? D[2ks][i] : D[2ks+1][i];  s32 = lg<2 ? D[2ks+1][i] : D[2ks][i];
//   r16/r32/r48 = shfl_xor(s16,16)/(s32,32)/(s32,48);
//   u[j=i]  : lg0->D[2ks][i], lg1->r48, lg2->r32, lg3->r16
//   u[j=2+i]: lg0->r16, lg1->r32, lg2->r48, lg3->D[2ks+1][i]
#define K_OFF(buf)  ((buf) * 8192)                    /* [64k][64d] bf16, XOR-swizzled rows */
#define V_OFF(buf)  (16384 + (buf) * 9216)            /* V^T: [64d][32 kpair dword], stride 36 dw */
#define LDS_BYTES   34816

__global__ __launch_bounds__(256, 3) void attn_mfma(
    const unsigned short* __restrict__ qh, const unsigned short* __restrict__ kh,
    const unsigned short* __restrict__ vh, const unsigned short* __restrict__ rb,
    unsigned short* __restrict__ ctx)
{
    __shared__ __align__(16) unsigned char lds[LDS_BYTES];
    const int tid  = threadIdx.x;
    const int lane = tid & 63;
    const int wave = tid >> 6;
    const int qn   = lane & 15;
    const int lg   = lane >> 4;
    const int bh = blockIdx.y;
    const int b = bh >> 4, h = bh & 15;
    const int g = h >> 2;
    const int qt = 15 - (int)blockIdx.x;        // heavy q-tiles first
    const int qw0 = qt * 64 + wave * 16;
    const int qg  = qw0 + qn;
    const int nch = qt + 1;                     // 64-key chunks

    const unsigned short* kbase = kh + (size_t)b * TSEQ * KVDIM + g * HDIM;
    const unsigned short* vbase = vh + (size_t)b * TSEQ * KVDIM + g * HDIM;

    // Q fragments: col q=qn, rows d = dh*32 + lg*8 + i
    bf16x8 qf[2];
    {
        const unsigned short* qp = qh + (size_t)(b * TSEQ + qg) * DMODEL + h * HDIM;
        qf[0] = *(const bf16x8*)(qp + lg * 8);
        qf[1] = *(const bf16x8*)(qp + 32 + lg * 8);
    }
    const unsigned short* rbbase = rb + ((size_t)(b * TSEQ + qg) * NHEAD + h) * 128;
    const float cb = b2f(rbbase[127]);

    // staging thread mapping (64 keys)
    const int sk  = tid >> 2;            // K row 0..63
    const int sd0 = (tid & 3) << 4;      // K d-start elems (0,16,32,48), 2x bf16x8 each
    const int vkp = tid >> 3;            // V kpair 0..31
    const int vd0 = (tid & 7) << 3;      // V d-start elems (0,8,..,56), 8 dwords each

    f32x4 oa0 = {0.f,0.f,0.f,0.f}, oa1 = oa0, oa2 = oa0, oa3 = oa0;
    float mReg = -1e30f, lReg = 0.f;

    // ---- prologue: stage chunk 0 ----
    {
        bf16x8 kx0 = *(const bf16x8*)(kbase + (size_t)sk * KVDIM + sd0);
        bf16x8 kx1 = *(const bf16x8*)(kbase + (size_t)sk * KVDIM + sd0 + 8);
        uint4 va = *(const uint4*)(vbase + (size_t)(2 * vkp) * KVDIM + vd0);
        uint4 vvb = *(const uint4*)(vbase + (size_t)(2 * vkp + 1) * KVDIM + vd0);
        unsigned char* kd = lds + K_OFF(0) + sk * 128;
        const int sw = (sk & 7) << 4;
        *(bf16x8*)(kd + ((sd0 * 2) ^ sw)) = kx0;
        *(bf16x8*)(kd + ((sd0 * 2 + 16) ^ sw)) = kx1;
        unsigned char* vd = lds + V_OFF(0);
        const unsigned* ua = (const unsigned*)&va;
        const unsigned* ub = (const unsigned*)&vvb;
        #pragma unroll
        for (int j = 0; j < 8; j++) {
            unsigned lo = (ua[j >> 1] >> ((j & 1) * 16)) & 0xFFFFu;
            unsigned hi = (ub[j >> 1] >> ((j & 1) * 16)) & 0xFFFFu;
            *(unsigned*)(vd + (((vd0 + j) * 36 + vkp) * 4)) = lo | (hi << 16);
        }
    }
    __syncthreads();

    for (int c = 0; c < nch; c++) {
        const unsigned char* kbuf = lds + K_OFF(c & 1);
        const unsigned char* vbuf = lds + V_OFF(c & 1);
        // T14: issue next-chunk global loads early
        bf16x8 kx0, kx1; uint4 va, vvb;
        const bool stage = (c + 1 < nch);
        if (stage) {
            const int k0n = (c + 1) * 64;
            kx0 = *(const bf16x8*)(kbase + (size_t)(k0n + sk) * KVDIM + sd0);
            kx1 = *(const bf16x8*)(kbase + (size_t)(k0n + sk) * KVDIM + sd0 + 8);
            va  = *(const uint4*)(vbase + (size_t)(k0n + 2 * vkp) * KVDIM + vd0);
            vvb = *(const uint4*)(vbase + (size_t)(k0n + 2 * vkp + 1) * KVDIM + vd0);
        }
        {
            const int k0 = c * 64;
            float sa[4][4];
            const bool far = (qw0 - k0) >= 190;
            #pragma unroll
            for (int kt = 0; kt < 4; kt++)
                #pragma unroll
                for (int r = 0; r < 4; r++) {
                    if (far) { sa[kt][r] = cb; }
                    else {
                        int dist = qg - (k0 + kt * 16 + lg * 4 + r);
                        sa[kt][r] = (dist < 0) ? -1e30f : b2f(rbbase[min(dist, 127)]);
                    }
                }
            f32x4 acc[4];
            #pragma unroll
            for (int kt = 0; kt < 4; kt++)
                acc[kt] = (f32x4){sa[kt][0], sa[kt][1], sa[kt][2], sa[kt][3]};
            #pragma unroll
            for (int dh = 0; dh < 2; dh++) {
                #pragma unroll
                for (int kt = 0; kt < 4; kt++) {
                    const int kr = kt * 16 + qn;
                    bf16x8 kf = *(const bf16x8*)(kbuf + kr * 128 + ((dh * 64 + lg * 16) ^ ((kr & 7) << 4)));
                    acc[kt] = __builtin_amdgcn_mfma_f32_16x16x32_bf16(kf, qf[dh], acc[kt], 0, 0, 0);
                }
            }
            #pragma unroll
            for (int kt = 0; kt < 4; kt++) {
                sa[kt][0] = acc[kt][0]; sa[kt][1] = acc[kt][1];
                sa[kt][2] = acc[kt][2]; sa[kt][3] = acc[kt][3];
            }
            float mt = -1e30f;
            #pragma unroll
            for (int kt = 0; kt < 4; kt++)
                mt = fmaxf(mt, fmaxf(fmaxf(sa[kt][0], sa[kt][1]), fmaxf(sa[kt][2], sa[kt][3])));
            mt = fmaxf(mt, __shfl_xor(mt, 16));
            mt = fmaxf(mt, __shfl_xor(mt, 32));
            if (!__all(mt <= mReg + 8.0f)) {       // defer-max (T13)
                float mn = fmaxf(mReg, mt);
                float sc = __expf(mReg - mn);
                lReg *= sc;
                oa0 *= sc; oa1 *= sc; oa2 *= sc; oa3 *= sc;
                mReg = mn;
            }
            float ls = 0.f;
            #pragma unroll
            for (int kt = 0; kt < 4; kt++)
                #pragma unroll
                for (int r = 0; r < 4; r++) {
                    float e = __expf(sa[kt][r] - mReg);   // masked -> exp(-1e30)=0
                    sa[kt][r] = e; ls += e;
                }
            ls += __shfl_xor(ls, 16);
            ls += __shfl_xor(ls, 32);
            lReg += ls;
            // ---- P -> bf16 B-frags fully in registers (shfl_xor permutation) ----
            unsigned D[4][2];
            #pragma unroll
            for (int kt = 0; kt < 4; kt++)
                #pragma unroll
                for (int i = 0; i < 2; i++)
                    D[kt][i] = f2b_pack(sa[kt][2 * i], sa[kt][2 * i + 1]);
            union { unsigned u[4]; bf16x8 v; } pf[2];
            #pragma unroll
            for (int ks = 0; ks < 2; ks++) {
                #pragma unroll
                for (int i = 0; i < 2; i++) {
                    const unsigned A_ = D[2 * ks][i];
                    const unsigned B_ = D[2 * ks + 1][i];
                    const unsigned s16 = (lg < 2) ? A_ : B_;
                    const unsigned s32 = (lg < 2) ? B_ : A_;
                    const unsigned r16 = __shfl_xor(s16, 16);
                    const unsigned r32 = __shfl_xor(s32, 32);
                    const unsigned r48 = __shfl_xor(s32, 48);
                    pf[ks].u[i]     = (lg == 0) ? A_ : (lg == 1) ? r48 : (lg == 2) ? r32 : r16;
                    pf[ks].u[2 + i] = (lg == 3) ? B_ : (lg == 2) ? r48 : (lg == 1) ? r32 : r16;
                }
            }
            #pragma unroll
            for (int ks = 0; ks < 2; ks++) {
                bf16x8 vf0 = *(const bf16x8*)(vbuf + (((0 * 16 + qn) * 36 + ks * 16 + lg * 4) * 4));
                oa0 = __builtin_amdgcn_mfma_f32_16x16x32_bf16(vf0, pf[ks].v, oa0, 0, 0, 0);
                bf16x8 vf1 = *(const bf16x8*)(vbuf + (((1 * 16 + qn) * 36 + ks * 16 + lg * 4) * 4));
                oa1 = __builtin_amdgcn_mfma_f32_16x16x32_bf16(vf1, pf[ks].v, oa1, 0, 0, 0);
                bf16x8 vf2 = *(const bf16x8*)(vbuf + (((2 * 16 + qn) * 36 + ks * 16 + lg * 4) * 4));
                oa2 = __builtin_amdgcn_mfma_f32_16x16x32_bf16(vf2, pf[ks].v, oa2, 0, 0, 0);
                bf16x8 vf3 = *(const bf16x8*)(vbuf + (((3 * 16 + qn) * 36 + ks * 16 + lg * 4) * 4));
                oa3 = __builtin_amdgcn_mfma_f32_16x16x32_bf16(vf3, pf[ks].v, oa3, 0, 0, 0);
            }
        }
        if (stage) {
            unsigned char* kd = lds + K_OFF((c + 1) & 1) + sk * 128;
            const int sw = (sk & 7) << 4;
            *(bf16x8*)(kd + ((sd0 * 2) ^ sw)) = kx0;
            *(bf16x8*)(kd + ((sd0 * 2 + 16) ^ sw)) = kx1;
            unsigned char* vd = lds + V_OFF((c + 1) & 1);
            const unsigned* ua = (const unsigned*)&va;
            const unsigned* ub = (const unsigned*)&vvb;
            #pragma unroll
            for (int j = 0; j < 8; j++) {
                unsigned lo = (ua[j >> 1] >> ((j & 1) * 16)) & 0xFFFFu;
                unsigned hi = (ub[j >> 1] >> ((j & 1) * 16)) & 0xFFFFu;
                *(unsigned*)(vd + (((vd0 + j) * 36 + vkp) * 4)) = lo | (hi << 16);
            }
        }
        __syncthreads();
    }

    // epilogue: O^T rows d = dt*16 + lg*4 + r, col q = qn -> bf16 ctx
    const float iL = 1.0f / lReg;
    unsigned short* op = ctx + (size_t)(b * TSEQ + qg) * DMODEL + h * HDIM;
    uint2 s;
    s.x = f2b_pack(oa0[0] * iL, oa0[1] * iL); s.y = f2b_pack(oa0[2] * iL, oa0[3] * iL);
    *(uint2*)(op + 0 * 16 + lg * 4) = s;
    s.x = f2b_pack(oa1[0] * iL, oa1[1] * iL); s.y = f2b_pack(oa1[2] * iL, oa1[3] * iL);
    *(uint2*)(op + 1 * 16 + lg * 4) = s;
    s.x = f2b_pack(oa2[0] * iL, oa2[1] * iL); s.y = f2b_pack(oa2[2] * iL, oa2[3] * iL);
    *(uint2*)(op + 2 * 16 + lg * 4) = s;
    s.x = f2b_pack(oa3[0] * iL, oa3[1] * iL); s.y = f2b_pack(oa3[2] * iL, oa3[3] * iL);
    *(uint2*)(op + 3 * 16 + lg * 4) = s;
}

extern "C" void kernel_launch(void* const* d_in, const int* in_sizes, int n_in,
                              void* d_out, int out_size, void* d_ws, size_t ws_size,
                              hipStream_t stream) {
    const float* q   = (const float*)d_in[0];
    const float* k   = (const float*)d_in[1];
    const float* v   = (const float*)d_in[2];
    const float* Wq  = (const float*)d_in[3];
    const float* Wk  = (const float*)d_in[4];
    const float* Wv  = (const float*)d_in[5];
    const float* Wo  = (const float*)d_in[6];
    const float* rel = (const float*)d_in[7];
    // d_in[8] = attn_mask: exactly causal (triu k=1) -> computed analytically.
    float* out = (float*)d_out;

    // workspace (ushort units); ~27 MB total
    unsigned short* qb   = (unsigned short*)d_ws;              // 2M
    unsigned short* kb   = qb   + (size_t)2048 * 1024;         // 2M
    unsigned short* vb   = kb   + (size_t)2048 * 1024;         // 2M
    unsigned short* WqT  = vb   + (size_t)2048 * 1024;         // 1M
    unsigned short* WkT  = WqT  + (size_t)1024 * 1024;         // 256K
    unsigned short* WvT  = WkT  + (size_t)256 * 1024;          // 256K
    unsigned short* WoT  = WvT  + (size_t)256 * 1024;          // 1M
    unsigned short* relb = WoT  + (size_t)1024 * 1024;         // 8K
    unsigned short* qh   = relb + 8192;                        // 2M
    unsigned short* kh   = qh   + (size_t)2048 * 1024;         // 512K
    unsigned short* vh   = kh   + (size_t)2048 * 256;          // 512K
    unsigned short* rbb  = vh   + (size_t)2048 * 256;          // 4M
    unsigned short* ctx  = qb;   // alias: qb dead after Q-projection

    prep<<<5636, 256, 0, stream>>>(q, k, v, rel, Wq, Wk, Wv, Wo,
                                   (unsigned*)qb, (unsigned*)kb, (unsigned*)vb,
                                   (unsigned*)relb, WqT, WkT, WvT, WoT);
    gemm_bt<true><<<dim3(16, 32), 256, 0, stream>>>(qb, WqT, qh, 2048, 1024, 1024, 0.125f);
    gemm_kv<<<dim3(4, 32, 2), 256, 0, stream>>>(kb, WkT, kh, vb, WvT, vh);
    // rb[(b,t,h)][j] = qh_row(64) . rel[127+j]   [32768,128] = [32768,64]@[128,64]^T
    gemm_bt<true><<<dim3(2, 512), 256, 0, stream>>>(qh, relb, rbb, 32768, 128, 64, 1.0f);
    attn_mfma<<<dim3(16, 32), 256, 0, stream>>>(qh, kh, vh, rbb, ctx);
    gemm_bt<false><<<dim3(16, 32), 256, 0, stream>>>(ctx, WoT, out, 2048, 1024, 1024, 1.0f);
}

// Round 13
// 94.218 us; speedup vs baseline: 1.1493x; 1.1405x over previous
//
#include <hip/hip_runtime.h>
#include <hip/hip_bf16.h>

#define TSEQ 1024
#define DMODEL 1024
#define NHEAD 16
#define NKV 4
#define HDIM 64
#define KVDIM 256   /* NKV*HDIM */
#define NBATCH 2

typedef __attribute__((ext_vector_type(4))) float f32x4;
typedef __attribute__((ext_vector_type(8))) short bf16x8;

// ---------- helpers ----------
__device__ __forceinline__ unsigned f2b_pack(float a, float b) {
    unsigned ua = __float_as_uint(a);
    ua = (ua + 0x7FFFu + ((ua >> 16) & 1u)) >> 16;
    unsigned ub = __float_as_uint(b);
    ub = (ub + 0x7FFFu + ((ub >> 16) & 1u)) & 0xFFFF0000u;
    return ua | ub;
}
__device__ __forceinline__ unsigned short f2b1(float x) {
    unsigned u = __float_as_uint(x);
    u = (u + 0x7FFFu + ((u >> 16) & 1u)) >> 16;
    return (unsigned short)u;
}
__device__ __forceinline__ float b2f(unsigned short u) {
    return __uint_as_float(((unsigned)u) << 16);
}
__device__ __forceinline__ void gload16(const void* g, void* l) {
    __builtin_amdgcn_global_load_lds(
        (const __attribute__((address_space(1))) void*)g,
        (__attribute__((address_space(3))) void*)l, 16, 0, 0);
}

// ---------- fused prep: q/k/v/rel f32->bf16 converts + 4 weight transposes ----------
__global__ __launch_bounds__(256) void prep(
    const float* __restrict__ q, const float* __restrict__ k,
    const float* __restrict__ v, const float* __restrict__ rel,
    const float* __restrict__ Wq, const float* __restrict__ Wk,
    const float* __restrict__ Wv, const float* __restrict__ Wo,
    unsigned* __restrict__ qb, unsigned* __restrict__ kb,
    unsigned* __restrict__ vb, unsigned* __restrict__ relb,
    unsigned short* __restrict__ WqT, unsigned short* __restrict__ WkT,
    unsigned short* __restrict__ WvT, unsigned short* __restrict__ WoT)
{
    const int bid = blockIdx.x;
    if (bid < 3072) {
        const float* src = bid < 1024 ? q : (bid < 2048 ? k : v);
        unsigned* dst = bid < 1024 ? qb : (bid < 2048 ? kb : vb);
        int i = (bid & 1023) * 256 + threadIdx.x;
        const float4* s = (const float4*)(src + (size_t)i * 8);
        float4 a = s[0], b = s[1];
        uint4 o = { f2b_pack(a.x, a.y), f2b_pack(a.z, a.w),
                    f2b_pack(b.x, b.y), f2b_pack(b.z, b.w) };
        ((uint4*)dst)[i] = o;
        return;
    }
    if (bid < 3076) {
        int i = (bid - 3072) * 256 + threadIdx.x;
        const float4* s = (const float4*)(rel + (size_t)127 * 64 + (size_t)i * 8);
        float4 a = s[0], b = s[1];
        uint4 o = { f2b_pack(a.x, a.y), f2b_pack(a.z, a.w),
                    f2b_pack(b.x, b.y), f2b_pack(b.z, b.w) };
        ((uint4*)relb)[i] = o;
        return;
    }
    const float* W; unsigned short* WT; int N, l;
    if (bid < 4100)      { W = Wq; WT = WqT; N = 1024; l = bid - 3076; }
    else if (bid < 4356) { W = Wk; WT = WkT; N = 256;  l = bid - 4100; }
    else if (bid < 4612) { W = Wv; WT = WvT; N = 256;  l = bid - 4356; }
    else                 { W = Wo; WT = WoT; N = 1024; l = bid - 4612; }
    const int nbx = N >> 5;
    const int n0 = (l % nbx) * 32, k0 = (l / nbx) * 32;
    __shared__ float t[32][33];
    const int tx = threadIdx.x & 31, ty = threadIdx.x >> 5;
    #pragma unroll
    for (int i = 0; i < 4; i++)
        t[ty + i * 8][tx] = W[(size_t)(k0 + ty + i * 8) * N + n0 + tx];
    __syncthreads();
    #pragma unroll
    for (int i = 0; i < 4; i++)
        WT[(size_t)(n0 + ty + i * 8) * 1024 + k0 + tx] = f2b1(t[tx][ty + i * 8]);
}

// ---------- bf16 MFMA GEMM body: C[M,N] = alpha * A[M,K] @ BT[N,K]^T ----------
template<bool OUTBF16>
__device__ __forceinline__ void gemm_body(
    const unsigned short* __restrict__ A, const unsigned short* __restrict__ BT,
    void* __restrict__ Cv, int M, int N, int K, float alpha)
{
    __shared__ __attribute__((aligned(16))) unsigned short As[64 * 64];
    __shared__ __attribute__((aligned(16))) unsigned short Bs[64 * 64];
    const int tid = threadIdx.x;
    const int lane = tid & 63, wave = tid >> 6;
    const int wr = wave >> 1, wc = wave & 1;
    const int m0 = blockIdx.y * 64, n0 = blockIdx.x * 64;
    const int qn = lane & 15, lg8 = (lane >> 4) * 8;
    const int rsub = lane >> 3, cb8 = (lane & 7) * 8;

    const unsigned short* aSrc = A + (size_t)(m0 + wave * 16 + rsub) * K + cb8;
    const unsigned short* bSrc = BT + (size_t)(n0 + wave * 16 + rsub) * K + cb8;

    f32x4 acc[2][2];
    #pragma unroll
    for (int x = 0; x < 2; x++)
        #pragma unroll
        for (int y = 0; y < 2; y++)
            acc[x][y] = (f32x4){0.f, 0.f, 0.f, 0.f};

    for (int k0 = 0; k0 < K; k0 += 64) {
        #pragma unroll
        for (int i = 0; i < 2; i++)
            gload16(aSrc + (size_t)i * 8 * K + k0, &As[(wave * 2 + i) * 512]);
        #pragma unroll
        for (int i = 0; i < 2; i++)
            gload16(bSrc + (size_t)i * 8 * K + k0, &Bs[(wave * 2 + i) * 512]);
        __syncthreads();
        #pragma unroll
        for (int ks = 0; ks < 2; ks++) {
            bf16x8 af[2], bfr[2];
            #pragma unroll
            for (int x = 0; x < 2; x++)
                af[x] = *(const bf16x8*)&As[(wr * 32 + x * 16 + qn) * 64 + ks * 32 + lg8];
            #pragma unroll
            for (int y = 0; y < 2; y++)
                bfr[y] = *(const bf16x8*)&Bs[(wc * 32 + y * 16 + qn) * 64 + ks * 32 + lg8];
            #pragma unroll
            for (int x = 0; x < 2; x++)
                #pragma unroll
                for (int y = 0; y < 2; y++)
                    acc[x][y] = __builtin_amdgcn_mfma_f32_16x16x32_bf16(af[x], bfr[y], acc[x][y], 0, 0, 0);
        }
        __syncthreads();
    }
    const int r4 = (lane >> 4) * 4;
    #pragma unroll
    for (int x = 0; x < 2; x++)
        #pragma unroll
        for (int y = 0; y < 2; y++) {
            const int row = m0 + wr * 32 + x * 16 + r4;
            const int col = n0 + wc * 32 + y * 16 + qn;
            #pragma unroll
            for (int r = 0; r < 4; r++) {
                float vv = acc[x][y][r] * alpha;
                if (OUTBF16)
                    ((unsigned short*)Cv)[(size_t)(row + r) * N + col] = f2b1(vv);
                else
                    ((float*)Cv)[(size_t)(row + r) * N + col] = vv;
            }
        }
}

template<bool OUTBF16>
__global__ __launch_bounds__(256) void gemm_bt(
    const unsigned short* __restrict__ A, const unsigned short* __restrict__ BT,
    void* __restrict__ Cv, int M, int N, int K, float alpha)
{
    gemm_body<OUTBF16>(A, BT, Cv, M, N, K, alpha);
}

__global__ __launch_bounds__(256) void gemm_kv(
    const unsigned short* __restrict__ kb, const unsigned short* __restrict__ WkT,
    unsigned short* __restrict__ kh,
    const unsigned short* __restrict__ vb, const unsigned short* __restrict__ WvT,
    unsigned short* __restrict__ vh)
{
    const unsigned short* A = blockIdx.z ? vb : kb;
    const unsigned short* B = blockIdx.z ? WvT : WkT;
    unsigned short* C = blockIdx.z ? vh : kh;
    gemm_body<true>(A, B, C, 2048, 256, 1024, 1.0f);
}

// ---------- MFMA flash attention, KVBLK=64 (round-5 verified kernel) ----------
// + FUSED rel-bias tile: rb[q_local][j] computed in-kernel (A-frags == qf,
//   B = relb from L2), stored bf16 in LDS stride 129; C-init reads LDS.
#define K_OFF(buf)  ((buf) * 8192)                    /* [64k][64d] bf16, XOR-swizzled rows */
#define V_OFF(buf)  (16384 + (buf) * 9216)            /* V^T: [64d][32 kpair dword], stride 36 dw */
#define P_OFF(w)    (34816 + (w) * 2176)              /* per-wave P^T: [32 kpair][16 q], stride 17 dw */
#define RB_OFF      43520                             /* rb tile: [64 q][129 stride] bf16 */
#define LDS_BYTES   60032

__global__ __launch_bounds__(256, 2) void attn_mfma(
    const unsigned short* __restrict__ qh, const unsigned short* __restrict__ kh,
    const unsigned short* __restrict__ vh, const unsigned short* __restrict__ relb,
    unsigned short* __restrict__ ctx)
{
    __shared__ __align__(16) unsigned char lds[LDS_BYTES];
    const int tid  = threadIdx.x;
    const int lane = tid & 63;
    const int wave = tid >> 6;
    const int qn   = lane & 15;
    const int lg   = lane >> 4;
    const int bh = blockIdx.y;
    const int b = bh >> 4, h = bh & 15;
    const int g = h >> 2;
    const int qt = 15 - (int)blockIdx.x;        // heavy q-tiles first
    const int qw0 = qt * 64 + wave * 16;
    const int qg  = qw0 + qn;
    const int nch = qt + 1;                     // 64-key chunks

    const unsigned short* kbase = kh + (size_t)b * TSEQ * KVDIM + g * HDIM;
    const unsigned short* vbase = vh + (size_t)b * TSEQ * KVDIM + g * HDIM;

    // Q fragments: col q=qn, rows d = dh*32 + lg*8 + i
    bf16x8 qf[2];
    {
        const unsigned short* qp = qh + (size_t)(b * TSEQ + qg) * DMODEL + h * HDIM;
        qf[0] = *(const bf16x8*)(qp + lg * 8);
        qf[1] = *(const bf16x8*)(qp + 32 + lg * 8);
    }

    // ---- fused rel-bias tile: per wave rows wave*16..+15, all 128 j ----
    // Identical accumulation order & packing to the former rb GEMM -> bit-identical.
    {
        f32x4 racc[8];
        #pragma unroll
        for (int y = 0; y < 8; y++) racc[y] = (f32x4){0.f, 0.f, 0.f, 0.f};
        #pragma unroll
        for (int ks = 0; ks < 2; ks++)
            #pragma unroll
            for (int y = 0; y < 8; y++) {
                bf16x8 bfr = *(const bf16x8*)(relb + (y * 16 + qn) * 64 + ks * 32 + lg * 8);
                racc[y] = __builtin_amdgcn_mfma_f32_16x16x32_bf16(qf[ks], bfr, racc[y], 0, 0, 0);
            }
        unsigned short* rbw = (unsigned short*)(lds + RB_OFF) + (size_t)(wave * 16 + lg * 4) * 129;
        #pragma unroll
        for (int y = 0; y < 8; y++)
            #pragma unroll
            for (int r = 0; r < 4; r++)
                rbw[r * 129 + y * 16 + qn] = f2b1(racc[y][r]);
    }

    // staging thread mapping (64 keys)
    const int sk  = tid >> 2;            // K row 0..63
    const int sd0 = (tid & 3) << 4;      // K d-start elems (0,16,32,48), 2x bf16x8 each
    const int vkp = tid >> 3;            // V kpair 0..31
    const int vd0 = (tid & 7) << 3;      // V d-start elems (0,8,..,56), 8 dwords each

    f32x4 oa0 = {0.f,0.f,0.f,0.f}, oa1 = oa0, oa2 = oa0, oa3 = oa0;
    float mReg = -1e30f, lReg = 0.f;

    // ---- prologue: stage chunk 0 ----
    {
        bf16x8 kx0 = *(const bf16x8*)(kbase + (size_t)sk * KVDIM + sd0);
        bf16x8 kx1 = *(const bf16x8*)(kbase + (size_t)sk * KVDIM + sd0 + 8);
        uint4 va = *(const uint4*)(vbase + (size_t)(2 * vkp) * KVDIM + vd0);
        uint4 vvb = *(const uint4*)(vbase + (size_t)(2 * vkp + 1) * KVDIM + vd0);
        unsigned char* kd = lds + K_OFF(0) + sk * 128;
        const int sw = (sk & 7) << 4;
        *(bf16x8*)(kd + ((sd0 * 2) ^ sw)) = kx0;
        *(bf16x8*)(kd + ((sd0 * 2 + 16) ^ sw)) = kx1;
        unsigned char* vd = lds + V_OFF(0);
        const unsigned* ua = (const unsigned*)&va;
        const unsigned* ub = (const unsigned*)&vvb;
        #pragma unroll
        for (int j = 0; j < 8; j++) {
            unsigned lo = (ua[j >> 1] >> ((j & 1) * 16)) & 0xFFFFu;
            unsigned hi = (ub[j >> 1] >> ((j & 1) * 16)) & 0xFFFFu;
            *(unsigned*)(vd + (((vd0 + j) * 36 + vkp) * 4)) = lo | (hi << 16);
        }
    }
    __syncthreads();

    // per-lane rb row (in LDS) and clamped far bias
    const unsigned short* rbl = (const unsigned short*)(lds + RB_OFF) + (size_t)(wave * 16 + qn) * 129;
    const float cb = b2f(rbl[127]);

    for (int c = 0; c < nch; c++) {
        const unsigned char* kbuf = lds + K_OFF(c & 1);
        const unsigned char* vbuf = lds + V_OFF(c & 1);
        // T14: issue next-chunk global loads early
        bf16x8 kx0, kx1; uint4 va, vvb;
        const bool stage = (c + 1 < nch);
        if (stage) {
            const int k0n = (c + 1) * 64;
            kx0 = *(const bf16x8*)(kbase + (size_t)(k0n + sk) * KVDIM + sd0);
            kx1 = *(const bf16x8*)(kbase + (size_t)(k0n + sk) * KVDIM + sd0 + 8);
            va  = *(const uint4*)(vbase + (size_t)(k0n + 2 * vkp) * KVDIM + vd0);
            vvb = *(const uint4*)(vbase + (size_t)(k0n + 2 * vkp + 1) * KVDIM + vd0);
        }
        {
            const int k0 = c * 64;
            float sa[4][4];
            const bool far = (qw0 - k0) >= 190;
            #pragma unroll
            for (int kt = 0; kt < 4; kt++)
                #pragma unroll
                for (int r = 0; r < 4; r++) {
                    if (far) { sa[kt][r] = cb; }
                    else {
                        int dist = qg - (k0 + kt * 16 + lg * 4 + r);
                        sa[kt][r] = (dist < 0) ? -1e30f : b2f(rbl[min(dist, 127)]);
                    }
                }
            f32x4 acc[4];
            #pragma unroll
            for (int kt = 0; kt < 4; kt++)
                acc[kt] = (f32x4){sa[kt][0], sa[kt][1], sa[kt][2], sa[kt][3]};
            #pragma unroll
            for (int dh = 0; dh < 2; dh++) {
                #pragma unroll
                for (int kt = 0; kt < 4; kt++) {
                    const int kr = kt * 16 + qn;
                    bf16x8 kf = *(const bf16x8*)(kbuf + kr * 128 + ((dh * 64 + lg * 16) ^ ((kr & 7) << 4)));
                    acc[kt] = __builtin_amdgcn_mfma_f32_16x16x32_bf16(kf, qf[dh], acc[kt], 0, 0, 0);
                }
            }
            #pragma unroll
            for (int kt = 0; kt < 4; kt++) {
                sa[kt][0] = acc[kt][0]; sa[kt][1] = acc[kt][1];
                sa[kt][2] = acc[kt][2]; sa[kt][3] = acc[kt][3];
            }
            float mt = -1e30f;
            #pragma unroll
            for (int kt = 0; kt < 4; kt++)
                mt = fmaxf(mt, fmaxf(fmaxf(sa[kt][0], sa[kt][1]), fmaxf(sa[kt][2], sa[kt][3])));
            mt = fmaxf(mt, __shfl_xor(mt, 16));
            mt = fmaxf(mt, __shfl_xor(mt, 32));
            if (!__all(mt <= mReg + 8.0f)) {       // defer-max (T13)
                float mn = fmaxf(mReg, mt);
                float sc = __expf(mReg - mn);
                lReg *= sc;
                oa0 *= sc; oa1 *= sc; oa2 *= sc; oa3 *= sc;
                mReg = mn;
            }
            float ls = 0.f;
            #pragma unroll
            for (int kt = 0; kt < 4; kt++)
                #pragma unroll
                for (int r = 0; r < 4; r++) {
                    float e = __expf(sa[kt][r] - mReg);   // masked -> exp(-1e30)=0
                    sa[kt][r] = e; ls += e;
                }
            ls += __shfl_xor(ls, 16);
            ls += __shfl_xor(ls, 32);
            lReg += ls;
            // P^T -> per-wave LDS, read back as B-frags
            unsigned char* pb = lds + P_OFF(wave);
            #pragma unroll
            for (int kt = 0; kt < 4; kt++)
                #pragma unroll
                for (int i = 0; i < 2; i++) {
                    unsigned dw = f2b_pack(sa[kt][2 * i], sa[kt][2 * i + 1]);
                    *(unsigned*)(pb + ((kt * 8 + lg * 2 + i) * 17 + qn) * 4) = dw;
                }
            asm volatile("s_waitcnt lgkmcnt(0)" ::: "memory");
            __builtin_amdgcn_sched_barrier(0);                  // rule #18
            union { unsigned u[4]; bf16x8 v; } pf[2];
            #pragma unroll
            for (int ks = 0; ks < 2; ks++)
                #pragma unroll
                for (int j = 0; j < 4; j++)
                    pf[ks].u[j] = *(const unsigned*)(pb + (((ks * 16 + lg * 4 + j) * 17 + qn) * 4));
            #pragma unroll
            for (int ks = 0; ks < 2; ks++) {
                bf16x8 vf0 = *(const bf16x8*)(vbuf + (((0 * 16 + qn) * 36 + ks * 16 + lg * 4) * 4));
                oa0 = __builtin_amdgcn_mfma_f32_16x16x32_bf16(vf0, pf[ks].v, oa0, 0, 0, 0);
                bf16x8 vf1 = *(const bf16x8*)(vbuf + (((1 * 16 + qn) * 36 + ks * 16 + lg * 4) * 4));
                oa1 = __builtin_amdgcn_mfma_f32_16x16x32_bf16(vf1, pf[ks].v, oa1, 0, 0, 0);
                bf16x8 vf2 = *(const bf16x8*)(vbuf + (((2 * 16 + qn) * 36 + ks * 16 + lg * 4) * 4));
                oa2 = __builtin_amdgcn_mfma_f32_16x16x32_bf16(vf2, pf[ks].v, oa2, 0, 0, 0);
                bf16x8 vf3 = *(const bf16x8*)(vbuf + (((3 * 16 + qn) * 36 + ks * 16 + lg * 4) * 4));
                oa3 = __builtin_amdgcn_mfma_f32_16x16x32_bf16(vf3, pf[ks].v, oa3, 0, 0, 0);
            }
        }
        if (stage) {
            unsigned char* kd = lds + K_OFF((c + 1) & 1) + sk * 128;
            const int sw = (sk & 7) << 4;
            *(bf16x8*)(kd + ((sd0 * 2) ^ sw)) = kx0;
            *(bf16x8*)(kd + ((sd0 * 2 + 16) ^ sw)) = kx1;
            unsigned char* vd = lds + V_OFF((c + 1) & 1);
            const unsigned* ua = (const unsigned*)&va;
            const unsigned* ub = (const unsigned*)&vvb;
            #pragma unroll
            for (int j = 0; j < 8; j++) {
                unsigned lo = (ua[j >> 1] >> ((j & 1) * 16)) & 0xFFFFu;
                unsigned hi = (ub[j >> 1] >> ((j & 1) * 16)) & 0xFFFFu;
                *(unsigned*)(vd + (((vd0 + j) * 36 + vkp) * 4)) = lo | (hi << 16);
            }
        }
        __syncthreads();
    }

    // epilogue: O^T rows d = dt*16 + lg*4 + r, col q = qn -> bf16 ctx
    const float iL = 1.0f / lReg;
    unsigned short* op = ctx + (size_t)(b * TSEQ + qg) * DMODEL + h * HDIM;
    uint2 s;
    s.x = f2b_pack(oa0[0] * iL, oa0[1] * iL); s.y = f2b_pack(oa0[2] * iL, oa0[3] * iL);
    *(uint2*)(op + 0 * 16 + lg * 4) = s;
    s.x = f2b_pack(oa1[0] * iL, oa1[1] * iL); s.y = f2b_pack(oa1[2] * iL, oa1[3] * iL);
    *(uint2*)(op + 1 * 16 + lg * 4) = s;
    s.x = f2b_pack(oa2[0] * iL, oa2[1] * iL); s.y = f2b_pack(oa2[2] * iL, oa2[3] * iL);
    *(uint2*)(op + 2 * 16 + lg * 4) = s;
    s.x = f2b_pack(oa3[0] * iL, oa3[1] * iL); s.y = f2b_pack(oa3[2] * iL, oa3[3] * iL);
    *(uint2*)(op + 3 * 16 + lg * 4) = s;
}

extern "C" void kernel_launch(void* const* d_in, const int* in_sizes, int n_in,
                              void* d_out, int out_size, void* d_ws, size_t ws_size,
                              hipStream_t stream) {
    const float* q   = (const float*)d_in[0];
    const float* k   = (const float*)d_in[1];
    const float* v   = (const float*)d_in[2];
    const float* Wq  = (const float*)d_in[3];
    const float* Wk  = (const float*)d_in[4];
    const float* Wv  = (const float*)d_in[5];
    const float* Wo  = (const float*)d_in[6];
    const float* rel = (const float*)d_in[7];
    // d_in[8] = attn_mask: exactly causal (triu k=1) -> computed analytically.
    float* out = (float*)d_out;

    // workspace (ushort units); ~19 MB total
    unsigned short* qb   = (unsigned short*)d_ws;              // 2M
    unsigned short* kb   = qb   + (size_t)2048 * 1024;         // 2M
    unsigned short* vb   = kb   + (size_t)2048 * 1024;         // 2M
    unsigned short* WqT  = vb   + (size_t)2048 * 1024;         // 1M
    unsigned short* WkT  = WqT  + (size_t)1024 * 1024;         // 256K
    unsigned short* WvT  = WkT  + (size_t)256 * 1024;          // 256K
    unsigned short* WoT  = WvT  + (size_t)256 * 1024;          // 1M
    unsigned short* relb = WoT  + (size_t)1024 * 1024;         // 8K
    unsigned short* qh   = relb + 8192;                        // 2M
    unsigned short* kh   = qh   + (size_t)2048 * 1024;         // 512K
    unsigned short* vh   = kh   + (size_t)2048 * 256;          // 512K
    unsigned short* ctx  = qb;   // alias: qb dead after Q-projection

    prep<<<5636, 256, 0, stream>>>(q, k, v, rel, Wq, Wk, Wv, Wo,
                                   (unsigned*)qb, (unsigned*)kb, (unsigned*)vb,
                                   (unsigned*)relb, WqT, WkT, WvT, WoT);
    gemm_bt<true><<<dim3(16, 32), 256, 0, stream>>>(qb, WqT, qh, 2048, 1024, 1024, 0.125f);
    gemm_kv<<<dim3(4, 32, 2), 256, 0, stream>>>(kb, WkT, kh, vb, WvT, vh);
    attn_mfma<<<dim3(16, 32), 256, 0, stream>>>(qh, kh, vh, relb, ctx);
    gemm_bt<false><<<dim3(16, 32), 256, 0, stream>>>(ctx, WoT, out, 2048, 1024, 1024, 1.0f);
}

// Round 15
// 83.529 us; speedup vs baseline: 1.2964x; 1.1280x over previous
//
#include <hip/hip_runtime.h>
#include <hip/hip_bf16.h>

#define TSEQ 1024
#define DMODEL 1024
#define NHEAD 16
#define NKV 4
#define HDIM 64
#define KVDIM 256   /* NKV*HDIM */
#define NBATCH 2

typedef __attribute__((ext_vector_type(4))) float f32x4;
typedef __attribute__((ext_vector_type(8))) short bf16x8;

// ---------- helpers ----------
__device__ __forceinline__ unsigned f2b_pack(float a, float b) {
    unsigned ua = __float_as_uint(a);
    ua = (ua + 0x7FFFu + ((ua >> 16) & 1u)) >> 16;
    unsigned ub = __float_as_uint(b);
    ub = (ub + 0x7FFFu + ((ub >> 16) & 1u)) & 0xFFFF0000u;
    return ua | ub;
}
__device__ __forceinline__ unsigned short f2b1(float x) {
    unsigned u = __float_as_uint(x);
    u = (u + 0x7FFFu + ((u >> 16) & 1u)) >> 16;
    return (unsigned short)u;
}
__device__ __forceinline__ float b2f(unsigned short u) {
    return __uint_as_float(((unsigned)u) << 16);
}
__device__ __forceinline__ void gload16(const void* g, void* l) {
    __builtin_amdgcn_global_load_lds(
        (const __attribute__((address_space(1))) void*)g,
        (__attribute__((address_space(3))) void*)l, 16, 0, 0);
}

// ---------- fused prep: q/k/v/rel f32->bf16 converts + 4 weight transposes ----------
__global__ __launch_bounds__(256) void prep(
    const float* __restrict__ q, const float* __restrict__ k,
    const float* __restrict__ v, const float* __restrict__ rel,
    const float* __restrict__ Wq, const float* __restrict__ Wk,
    const float* __restrict__ Wv, const float* __restrict__ Wo,
    unsigned* __restrict__ qb, unsigned* __restrict__ kb,
    unsigned* __restrict__ vb, unsigned* __restrict__ relb,
    unsigned short* __restrict__ WqT, unsigned short* __restrict__ WkT,
    unsigned short* __restrict__ WvT, unsigned short* __restrict__ WoT)
{
    const int bid = blockIdx.x;
    if (bid < 3072) {
        const float* src = bid < 1024 ? q : (bid < 2048 ? k : v);
        unsigned* dst = bid < 1024 ? qb : (bid < 2048 ? kb : vb);
        int i = (bid & 1023) * 256 + threadIdx.x;
        const float4* s = (const float4*)(src + (size_t)i * 8);
        float4 a = s[0], b = s[1];
        uint4 o = { f2b_pack(a.x, a.y), f2b_pack(a.z, a.w),
                    f2b_pack(b.x, b.y), f2b_pack(b.z, b.w) };
        ((uint4*)dst)[i] = o;
        return;
    }
    if (bid < 3076) {
        int i = (bid - 3072) * 256 + threadIdx.x;
        const float4* s = (const float4*)(rel + (size_t)127 * 64 + (size_t)i * 8);
        float4 a = s[0], b = s[1];
        uint4 o = { f2b_pack(a.x, a.y), f2b_pack(a.z, a.w),
                    f2b_pack(b.x, b.y), f2b_pack(b.z, b.w) };
        ((uint4*)relb)[i] = o;
        return;
    }
    const float* W; unsigned short* WT; int N, l;
    if (bid < 4100)      { W = Wq; WT = WqT; N = 1024; l = bid - 3076; }
    else if (bid < 4356) { W = Wk; WT = WkT; N = 256;  l = bid - 4100; }
    else if (bid < 4612) { W = Wv; WT = WvT; N = 256;  l = bid - 4356; }
    else                 { W = Wo; WT = WoT; N = 1024; l = bid - 4612; }
    const int nbx = N >> 5;
    const int n0 = (l % nbx) * 32, k0 = (l / nbx) * 32;
    __shared__ float t[32][33];
    const int tx = threadIdx.x & 31, ty = threadIdx.x >> 5;
    #pragma unroll
    for (int i = 0; i < 4; i++)
        t[ty + i * 8][tx] = W[(size_t)(k0 + ty + i * 8) * N + n0 + tx];
    __syncthreads();
    #pragma unroll
    for (int i = 0; i < 4; i++)
        WT[(size_t)(n0 + ty + i * 8) * 1024 + k0 + tx] = f2b1(t[tx][ty + i * 8]);
}

// ---------- bf16 MFMA GEMM body: C[M,N] = alpha * A[M,K] @ BT[N,K]^T ----------
template<bool OUTBF16>
__device__ __forceinline__ void gemm_body(
    const unsigned short* __restrict__ A, const unsigned short* __restrict__ BT,
    void* __restrict__ Cv, int M, int N, int K, float alpha)
{
    __shared__ __attribute__((aligned(16))) unsigned short As[64 * 64];
    __shared__ __attribute__((aligned(16))) unsigned short Bs[64 * 64];
    const int tid = threadIdx.x;
    const int lane = tid & 63, wave = tid >> 6;
    const int wr = wave >> 1, wc = wave & 1;
    const int m0 = blockIdx.y * 64, n0 = blockIdx.x * 64;
    const int qn = lane & 15, lg8 = (lane >> 4) * 8;
    const int rsub = lane >> 3, cb8 = (lane & 7) * 8;

    const unsigned short* aSrc = A + (size_t)(m0 + wave * 16 + rsub) * K + cb8;
    const unsigned short* bSrc = BT + (size_t)(n0 + wave * 16 + rsub) * K + cb8;

    f32x4 acc[2][2];
    #pragma unroll
    for (int x = 0; x < 2; x++)
        #pragma unroll
        for (int y = 0; y < 2; y++)
            acc[x][y] = (f32x4){0.f, 0.f, 0.f, 0.f};

    for (int k0 = 0; k0 < K; k0 += 64) {
        #pragma unroll
        for (int i = 0; i < 2; i++)
            gload16(aSrc + (size_t)i * 8 * K + k0, &As[(wave * 2 + i) * 512]);
        #pragma unroll
        for (int i = 0; i < 2; i++)
            gload16(bSrc + (size_t)i * 8 * K + k0, &Bs[(wave * 2 + i) * 512]);
        __syncthreads();
        #pragma unroll
        for (int ks = 0; ks < 2; ks++) {
            bf16x8 af[2], bfr[2];
            #pragma unroll
            for (int x = 0; x < 2; x++)
                af[x] = *(const bf16x8*)&As[(wr * 32 + x * 16 + qn) * 64 + ks * 32 + lg8];
            #pragma unroll
            for (int y = 0; y < 2; y++)
                bfr[y] = *(const bf16x8*)&Bs[(wc * 32 + y * 16 + qn) * 64 + ks * 32 + lg8];
            #pragma unroll
            for (int x = 0; x < 2; x++)
                #pragma unroll
                for (int y = 0; y < 2; y++)
                    acc[x][y] = __builtin_amdgcn_mfma_f32_16x16x32_bf16(af[x], bfr[y], acc[x][y], 0, 0, 0);
        }
        __syncthreads();
    }
    const int r4 = (lane >> 4) * 4;
    #pragma unroll
    for (int x = 0; x < 2; x++)
        #pragma unroll
        for (int y = 0; y < 2; y++) {
            const int row = m0 + wr * 32 + x * 16 + r4;
            const int col = n0 + wc * 32 + y * 16 + qn;
            #pragma unroll
            for (int r = 0; r < 4; r++) {
                float vv = acc[x][y][r] * alpha;
                if (OUTBF16)
                    ((unsigned short*)Cv)[(size_t)(row + r) * N + col] = f2b1(vv);
                else
                    ((float*)Cv)[(size_t)(row + r) * N + col] = vv;
            }
        }
}

template<bool OUTBF16>
__global__ __launch_bounds__(256) void gemm_bt(
    const unsigned short* __restrict__ A, const unsigned short* __restrict__ BT,
    void* __restrict__ Cv, int M, int N, int K, float alpha)
{
    gemm_body<OUTBF16>(A, BT, Cv, M, N, K, alpha);
}

// ---------- merged QKV projection: per-n-block A AND C routing ----------
// BTcat = WqT|WkT|WvT (contiguous rows 0..1535).
// n0<1024: A=qb -> qh (alpha 0.125); n0<1280: A=kb -> kh; else: A=vb -> vh.
__global__ __launch_bounds__(256) void gemm_qkv(
    const unsigned short* __restrict__ qb, const unsigned short* __restrict__ kb,
    const unsigned short* __restrict__ vb, const unsigned short* __restrict__ BTcat,
    unsigned short* __restrict__ qh, unsigned short* __restrict__ kh,
    unsigned short* __restrict__ vh)
{
    __shared__ __attribute__((aligned(16))) unsigned short As[64 * 64];
    __shared__ __attribute__((aligned(16))) unsigned short Bs[64 * 64];
    const int tid = threadIdx.x;
    const int lane = tid & 63, wave = tid >> 6;
    const int wr = wave >> 1, wc = wave & 1;
    const int m0 = blockIdx.y * 64, n0 = blockIdx.x * 64;
    const int qn = lane & 15, lg8 = (lane >> 4) * 8;
    const int rsub = lane >> 3, cb8 = (lane & 7) * 8;
    const int K = 1024;

    // route A and C by n-block (uniform per block)
    const unsigned short* Abase; unsigned short* Cbase; int Nout, coff; float alpha;
    if (n0 < 1024)      { Abase = qb; Cbase = qh; Nout = 1024; coff = n0;        alpha = 0.125f; }
    else if (n0 < 1280) { Abase = kb; Cbase = kh; Nout = 256;  coff = n0 - 1024; alpha = 1.0f; }
    else                { Abase = vb; Cbase = vh; Nout = 256;  coff = n0 - 1280; alpha = 1.0f; }

    const unsigned short* aSrc = Abase + (size_t)(m0 + wave * 16 + rsub) * K + cb8;
    const unsigned short* bSrc = BTcat + (size_t)(n0 + wave * 16 + rsub) * K + cb8;

    f32x4 acc[2][2];
    #pragma unroll
    for (int x = 0; x < 2; x++)
        #pragma unroll
        for (int y = 0; y < 2; y++)
            acc[x][y] = (f32x4){0.f, 0.f, 0.f, 0.f};

    for (int k0 = 0; k0 < K; k0 += 64) {
        #pragma unroll
        for (int i = 0; i < 2; i++)
            gload16(aSrc + (size_t)i * 8 * K + k0, &As[(wave * 2 + i) * 512]);
        #pragma unroll
        for (int i = 0; i < 2; i++)
            gload16(bSrc + (size_t)i * 8 * K + k0, &Bs[(wave * 2 + i) * 512]);
        __syncthreads();
        #pragma unroll
        for (int ks = 0; ks < 2; ks++) {
            bf16x8 af[2], bfr[2];
            #pragma unroll
            for (int x = 0; x < 2; x++)
                af[x] = *(const bf16x8*)&As[(wr * 32 + x * 16 + qn) * 64 + ks * 32 + lg8];
            #pragma unroll
            for (int y = 0; y < 2; y++)
                bfr[y] = *(const bf16x8*)&Bs[(wc * 32 + y * 16 + qn) * 64 + ks * 32 + lg8];
            #pragma unroll
            for (int x = 0; x < 2; x++)
                #pragma unroll
                for (int y = 0; y < 2; y++)
                    acc[x][y] = __builtin_amdgcn_mfma_f32_16x16x32_bf16(af[x], bfr[y], acc[x][y], 0, 0, 0);
        }
        __syncthreads();
    }
    const int r4 = (lane >> 4) * 4;
    #pragma unroll
    for (int x = 0; x < 2; x++)
        #pragma unroll
        for (int y = 0; y < 2; y++) {
            const int row = m0 + wr * 32 + x * 16 + r4;
            const int col = coff + wc * 32 + y * 16 + qn;
            #pragma unroll
            for (int r = 0; r < 4; r++)
                Cbase[(size_t)(row + r) * Nout + col] = f2b1(acc[x][y][r] * alpha);
        }
}

// ---------- MFMA flash attention, KVBLK=64 + fused rel-bias tile (round-13 verified) ----------
#define K_OFF(buf)  ((buf) * 8192)                    /* [64k][64d] bf16, XOR-swizzled rows */
#define V_OFF(buf)  (16384 + (buf) * 9216)            /* V^T: [64d][32 kpair dword], stride 36 dw */
#define P_OFF(w)    (34816 + (w) * 2176)              /* per-wave P^T: [32 kpair][16 q], stride 17 dw */
#define RB_OFF      43520                             /* rb tile: [64 q][129 stride] bf16 */
#define LDS_BYTES   60032

__global__ __launch_bounds__(256, 2) void attn_mfma(
    const unsigned short* __restrict__ qh, const unsigned short* __restrict__ kh,
    const unsigned short* __restrict__ vh, const unsigned short* __restrict__ relb,
    unsigned short* __restrict__ ctx)
{
    __shared__ __align__(16) unsigned char lds[LDS_BYTES];
    const int tid  = threadIdx.x;
    const int lane = tid & 63;
    const int wave = tid >> 6;
    const int qn   = lane & 15;
    const int lg   = lane >> 4;
    const int bh = blockIdx.y;
    const int b = bh >> 4, h = bh & 15;
    const int g = h >> 2;
    const int qt = 15 - (int)blockIdx.x;        // heavy q-tiles first
    const int qw0 = qt * 64 + wave * 16;
    const int qg  = qw0 + qn;
    const int nch = qt + 1;                     // 64-key chunks

    const unsigned short* kbase = kh + (size_t)b * TSEQ * KVDIM + g * HDIM;
    const unsigned short* vbase = vh + (size_t)b * TSEQ * KVDIM + g * HDIM;

    // Q fragments: col q=qn, rows d = dh*32 + lg*8 + i
    bf16x8 qf[2];
    {
        const unsigned short* qp = qh + (size_t)(b * TSEQ + qg) * DMODEL + h * HDIM;
        qf[0] = *(const bf16x8*)(qp + lg * 8);
        qf[1] = *(const bf16x8*)(qp + 32 + lg * 8);
    }

    // ---- fused rel-bias tile: per wave rows wave*16..+15, all 128 j ----
    {
        f32x4 racc[8];
        #pragma unroll
        for (int y = 0; y < 8; y++) racc[y] = (f32x4){0.f, 0.f, 0.f, 0.f};
        #pragma unroll
        for (int ks = 0; ks < 2; ks++)
            #pragma unroll
            for (int y = 0; y < 8; y++) {
                bf16x8 bfr = *(const bf16x8*)(relb + (y * 16 + qn) * 64 + ks * 32 + lg * 8);
                racc[y] = __builtin_amdgcn_mfma_f32_16x16x32_bf16(qf[ks], bfr, racc[y], 0, 0, 0);
            }
        unsigned short* rbw = (unsigned short*)(lds + RB_OFF) + (size_t)(wave * 16 + lg * 4) * 129;
        #pragma unroll
        for (int y = 0; y < 8; y++)
            #pragma unroll
            for (int r = 0; r < 4; r++)
                rbw[r * 129 + y * 16 + qn] = f2b1(racc[y][r]);
    }

    // staging thread mapping (64 keys)
    const int sk  = tid >> 2;            // K row 0..63
    const int sd0 = (tid & 3) << 4;      // K d-start elems (0,16,32,48), 2x bf16x8 each
    const int vkp = tid >> 3;            // V kpair 0..31
    const int vd0 = (tid & 7) << 3;      // V d-start elems (0,8,..,56), 8 dwords each

    f32x4 oa0 = {0.f,0.f,0.f,0.f}, oa1 = oa0, oa2 = oa0, oa3 = oa0;
    float mReg = -1e30f, lReg = 0.f;

    // ---- prologue: stage chunk 0 ----
    {
        bf16x8 kx0 = *(const bf16x8*)(kbase + (size_t)sk * KVDIM + sd0);
        bf16x8 kx1 = *(const bf16x8*)(kbase + (size_t)sk * KVDIM + sd0 + 8);
        uint4 va = *(const uint4*)(vbase + (size_t)(2 * vkp) * KVDIM + vd0);
        uint4 vvb = *(const uint4*)(vbase + (size_t)(2 * vkp + 1) * KVDIM + vd0);
        unsigned char* kd = lds + K_OFF(0) + sk * 128;
        const int sw = (sk & 7) << 4;
        *(bf16x8*)(kd + ((sd0 * 2) ^ sw)) = kx0;
        *(bf16x8*)(kd + ((sd0 * 2 + 16) ^ sw)) = kx1;
        unsigned char* vd = lds + V_OFF(0);
        const unsigned* ua = (const unsigned*)&va;
        const unsigned* ub = (const unsigned*)&vvb;
        #pragma unroll
        for (int j = 0; j < 8; j++) {
            unsigned lo = (ua[j >> 1] >> ((j & 1) * 16)) & 0xFFFFu;
            unsigned hi = (ub[j >> 1] >> ((j & 1) * 16)) & 0xFFFFu;
            *(unsigned*)(vd + (((vd0 + j) * 36 + vkp) * 4)) = lo | (hi << 16);
        }
    }
    __syncthreads();

    // per-lane rb row (in LDS) and clamped far bias
    const unsigned short* rbl = (const unsigned short*)(lds + RB_OFF) + (size_t)(wave * 16 + qn) * 129;
    const float cb = b2f(rbl[127]);

    for (int c = 0; c < nch; c++) {
        const unsigned char* kbuf = lds + K_OFF(c & 1);
        const unsigned char* vbuf = lds + V_OFF(c & 1);
        // T14: issue next-chunk global loads early
        bf16x8 kx0, kx1; uint4 va, vvb;
        const bool stage = (c + 1 < nch);
        if (stage) {
            const int k0n = (c + 1) * 64;
            kx0 = *(const bf16x8*)(kbase + (size_t)(k0n + sk) * KVDIM + sd0);
            kx1 = *(const bf16x8*)(kbase + (size_t)(k0n + sk) * KVDIM + sd0 + 8);
            va  = *(const uint4*)(vbase + (size_t)(k0n + 2 * vkp) * KVDIM + vd0);
            vvb = *(const uint4*)(vbase + (size_t)(k0n + 2 * vkp + 1) * KVDIM + vd0);
        }
        {
            const int k0 = c * 64;
            float sa[4][4];
            const bool far = (qw0 - k0) >= 190;
            #pragma unroll
            for (int kt = 0; kt < 4; kt++)
                #pragma unroll
                for (int r = 0; r < 4; r++) {
                    if (far) { sa[kt][r] = cb; }
                    else {
                        int dist = qg - (k0 + kt * 16 + lg * 4 + r);
                        sa[kt][r] = (dist < 0) ? -1e30f : b2f(rbl[min(dist, 127)]);
                    }
                }
            f32x4 acc[4];
            #pragma unroll
            for (int kt = 0; kt < 4; kt++)
                acc[kt] = (f32x4){sa[kt][0], sa[kt][1], sa[kt][2], sa[kt][3]};
            #pragma unroll
            for (int dh = 0; dh < 2; dh++) {
                #pragma unroll
                for (int kt = 0; kt < 4; kt++) {
                    const int kr = kt * 16 + qn;
                    bf16x8 kf = *(const bf16x8*)(kbuf + kr * 128 + ((dh * 64 + lg * 16) ^ ((kr & 7) << 4)));
                    acc[kt] = __builtin_amdgcn_mfma_f32_16x16x32_bf16(kf, qf[dh], acc[kt], 0, 0, 0);
                }
            }
            #pragma unroll
            for (int kt = 0; kt < 4; kt++) {
                sa[kt][0] = acc[kt][0]; sa[kt][1] = acc[kt][1];
                sa[kt][2] = acc[kt][2]; sa[kt][3] = acc[kt][3];
            }
            float mt = -1e30f;
            #pragma unroll
            for (int kt = 0; kt < 4; kt++)
                mt = fmaxf(mt, fmaxf(fmaxf(sa[kt][0], sa[kt][1]), fmaxf(sa[kt][2], sa[kt][3])));
            mt = fmaxf(mt, __shfl_xor(mt, 16));
            mt = fmaxf(mt, __shfl_xor(mt, 32));
            if (!__all(mt <= mReg + 8.0f)) {       // defer-max (T13)
                float mn = fmaxf(mReg, mt);
                float sc = __expf(mReg - mn);
                lReg *= sc;
                oa0 *= sc; oa1 *= sc; oa2 *= sc; oa3 *= sc;
                mReg = mn;
            }
            float ls = 0.f;
            #pragma unroll
            for (int kt = 0; kt < 4; kt++)
                #pragma unroll
                for (int r = 0; r < 4; r++) {
                    float e = __expf(sa[kt][r] - mReg);   // masked -> exp(-1e30)=0
                    sa[kt][r] = e; ls += e;
                }
            ls += __shfl_xor(ls, 16);
            ls += __shfl_xor(ls, 32);
            lReg += ls;
            // P^T -> per-wave LDS, read back as B-frags
            unsigned char* pb = lds + P_OFF(wave);
            #pragma unroll
            for (int kt = 0; kt < 4; kt++)
                #pragma unroll
                for (int i = 0; i < 2; i++) {
                    unsigned dw = f2b_pack(sa[kt][2 * i], sa[kt][2 * i + 1]);
                    *(unsigned*)(pb + ((kt * 8 + lg * 2 + i) * 17 + qn) * 4) = dw;
                }
            asm volatile("s_waitcnt lgkmcnt(0)" ::: "memory");
            __builtin_amdgcn_sched_barrier(0);                  // rule #18
            union { unsigned u[4]; bf16x8 v; } pf[2];
            #pragma unroll
            for (int ks = 0; ks < 2; ks++)
                #pragma unroll
                for (int j = 0; j < 4; j++)
                    pf[ks].u[j] = *(const unsigned*)(pb + (((ks * 16 + lg * 4 + j) * 17 + qn) * 4));
            #pragma unroll
            for (int ks = 0; ks < 2; ks++) {
                bf16x8 vf0 = *(const bf16x8*)(vbuf + (((0 * 16 + qn) * 36 + ks * 16 + lg * 4) * 4));
                oa0 = __builtin_amdgcn_mfma_f32_16x16x32_bf16(vf0, pf[ks].v, oa0, 0, 0, 0);
                bf16x8 vf1 = *(const bf16x8*)(vbuf + (((1 * 16 + qn) * 36 + ks * 16 + lg * 4) * 4));
                oa1 = __builtin_amdgcn_mfma_f32_16x16x32_bf16(vf1, pf[ks].v, oa1, 0, 0, 0);
                bf16x8 vf2 = *(const bf16x8*)(vbuf + (((2 * 16 + qn) * 36 + ks * 16 + lg * 4) * 4));
                oa2 = __builtin_amdgcn_mfma_f32_16x16x32_bf16(vf2, pf[ks].v, oa2, 0, 0, 0);
                bf16x8 vf3 = *(const bf16x8*)(vbuf + (((3 * 16 + qn) * 36 + ks * 16 + lg * 4) * 4));
                oa3 = __builtin_amdgcn_mfma_f32_16x16x32_bf16(vf3, pf[ks].v, oa3, 0, 0, 0);
            }
        }
        if (stage) {
            unsigned char* kd = lds + K_OFF((c + 1) & 1) + sk * 128;
            const int sw = (sk & 7) << 4;
            *(bf16x8*)(kd + ((sd0 * 2) ^ sw)) = kx0;
            *(bf16x8*)(kd + ((sd0 * 2 + 16) ^ sw)) = kx1;
            unsigned char* vd = lds + V_OFF((c + 1) & 1);
            const unsigned* ua = (const unsigned*)&va;
            const unsigned* ub = (const unsigned*)&vvb;
            #pragma unroll
            for (int j = 0; j < 8; j++) {
                unsigned lo = (ua[j >> 1] >> ((j & 1) * 16)) & 0xFFFFu;
                unsigned hi = (ub[j >> 1] >> ((j & 1) * 16)) & 0xFFFFu;
                *(unsigned*)(vd + (((vd0 + j) * 36 + vkp) * 4)) = lo | (hi << 16);
            }
        }
        __syncthreads();
    }

    // epilogue: O^T rows d = dt*16 + lg*4 + r, col q = qn -> bf16 ctx
    const float iL = 1.0f / lReg;
    unsigned short* op = ctx + (size_t)(b * TSEQ + qg) * DMODEL + h * HDIM;
    uint2 s;
    s.x = f2b_pack(oa0[0] * iL, oa0[1] * iL); s.y = f2b_pack(oa0[2] * iL, oa0[3] * iL);
    *(uint2*)(op + 0 * 16 + lg * 4) = s;
    s.x = f2b_pack(oa1[0] * iL, oa1[1] * iL); s.y = f2b_pack(oa1[2] * iL, oa1[3] * iL);
    *(uint2*)(op + 1 * 16 + lg * 4) = s;
    s.x = f2b_pack(oa2[0] * iL, oa2[1] * iL); s.y = f2b_pack(oa2[2] * iL, oa2[3] * iL);
    *(uint2*)(op + 2 * 16 + lg * 4) = s;
    s.x = f2b_pack(oa3[0] * iL, oa3[1] * iL); s.y = f2b_pack(oa3[2] * iL, oa3[3] * iL);
    *(uint2*)(op + 3 * 16 + lg * 4) = s;
}

extern "C" void kernel_launch(void* const* d_in, const int* in_sizes, int n_in,
                              void* d_out, int out_size, void* d_ws, size_t ws_size,
                              hipStream_t stream) {
    const float* q   = (const float*)d_in[0];
    const float* k   = (const float*)d_in[1];
    const float* v   = (const float*)d_in[2];
    const float* Wq  = (const float*)d_in[3];
    const float* Wk  = (const float*)d_in[4];
    const float* Wv  = (const float*)d_in[5];
    const float* Wo  = (const float*)d_in[6];
    const float* rel = (const float*)d_in[7];
    // d_in[8] = attn_mask: exactly causal (triu k=1) -> computed analytically.
    float* out = (float*)d_out;

    // workspace (ushort units); ~19 MB total.
    // WqT/WkT/WvT contiguous -> BTcat[1536][1024] for the merged QKV GEMM.
    unsigned short* qb   = (unsigned short*)d_ws;              // 2M
    unsigned short* kb   = qb   + (size_t)2048 * 1024;         // 2M
    unsigned short* vb   = kb   + (size_t)2048 * 1024;         // 2M
    unsigned short* WqT  = vb   + (size_t)2048 * 1024;         // 1M  (BTcat rows 0-1023)
    unsigned short* WkT  = WqT  + (size_t)1024 * 1024;         // 256K (rows 1024-1279)
    unsigned short* WvT  = WkT  + (size_t)256 * 1024;          // 256K (rows 1280-1535)
    unsigned short* WoT  = WvT  + (size_t)256 * 1024;          // 1M
    unsigned short* relb = WoT  + (size_t)1024 * 1024;         // 8K
    unsigned short* qh   = relb + 8192;                        // 2M
    unsigned short* kh   = qh   + (size_t)2048 * 1024;         // 512K
    unsigned short* vh   = kh   + (size_t)2048 * 256;          // 512K
    unsigned short* ctx  = qb;   // alias: qb dead after QKV projection

    prep<<<5636, 256, 0, stream>>>(q, k, v, rel, Wq, Wk, Wv, Wo,
                                   (unsigned*)qb, (unsigned*)kb, (unsigned*)vb,
                                   (unsigned*)relb, WqT, WkT, WvT, WoT);
    gemm_qkv<<<dim3(24, 32), 256, 0, stream>>>(qb, kb, vb, WqT, qh, kh, vh);
    attn_mfma<<<dim3(16, 32), 256, 0, stream>>>(qh, kh, vh, relb, ctx);
    gemm_bt<false><<<dim3(16, 32), 256, 0, stream>>>(ctx, WoT, out, 2048, 1024, 1024, 1.0f);
}

// Round 16
// 78.483 us; speedup vs baseline: 1.3798x; 1.0643x over previous
//
#include <hip/hip_runtime.h>
#include <hip/hip_bf16.h>

#define TSEQ 1024
#define DMODEL 1024
#define NHEAD 16
#define NKV 4
#define HDIM 64
#define KVDIM 256   /* NKV*HDIM */
#define NBATCH 2

typedef __attribute__((ext_vector_type(4))) float f32x4;
typedef __attribute__((ext_vector_type(8))) short bf16x8;

// ---------- helpers ----------
__device__ __forceinline__ unsigned f2b_pack(float a, float b) {
    unsigned ua = __float_as_uint(a);
    ua = (ua + 0x7FFFu + ((ua >> 16) & 1u)) >> 16;
    unsigned ub = __float_as_uint(b);
    ub = (ub + 0x7FFFu + ((ub >> 16) & 1u)) & 0xFFFF0000u;
    return ua | ub;
}
__device__ __forceinline__ unsigned short f2b1(float x) {
    unsigned u = __float_as_uint(x);
    u = (u + 0x7FFFu + ((u >> 16) & 1u)) >> 16;
    return (unsigned short)u;
}
__device__ __forceinline__ float b2f(unsigned short u) {
    return __uint_as_float(((unsigned)u) << 16);
}
__device__ __forceinline__ void gload16(const void* g, void* l) {
    __builtin_amdgcn_global_load_lds(
        (const __attribute__((address_space(1))) void*)g,
        (__attribute__((address_space(3))) void*)l, 16, 0, 0);
}

// ---------- fused prep: q/k/v/rel f32->bf16 converts + 4 weight transposes ----------
__global__ __launch_bounds__(256) void prep(
    const float* __restrict__ q, const float* __restrict__ k,
    const float* __restrict__ v, const float* __restrict__ rel,
    const float* __restrict__ Wq, const float* __restrict__ Wk,
    const float* __restrict__ Wv, const float* __restrict__ Wo,
    unsigned* __restrict__ qb, unsigned* __restrict__ kb,
    unsigned* __restrict__ vb, unsigned* __restrict__ relb,
    unsigned short* __restrict__ WqT, unsigned short* __restrict__ WkT,
    unsigned short* __restrict__ WvT, unsigned short* __restrict__ WoT)
{
    const int bid = blockIdx.x;
    if (bid < 3072) {
        const float* src = bid < 1024 ? q : (bid < 2048 ? k : v);
        unsigned* dst = bid < 1024 ? qb : (bid < 2048 ? kb : vb);
        int i = (bid & 1023) * 256 + threadIdx.x;
        const float4* s = (const float4*)(src + (size_t)i * 8);
        float4 a = s[0], b = s[1];
        uint4 o = { f2b_pack(a.x, a.y), f2b_pack(a.z, a.w),
                    f2b_pack(b.x, b.y), f2b_pack(b.z, b.w) };
        ((uint4*)dst)[i] = o;
        return;
    }
    if (bid < 3076) {
        int i = (bid - 3072) * 256 + threadIdx.x;
        const float4* s = (const float4*)(rel + (size_t)127 * 64 + (size_t)i * 8);
        float4 a = s[0], b = s[1];
        uint4 o = { f2b_pack(a.x, a.y), f2b_pack(a.z, a.w),
                    f2b_pack(b.x, b.y), f2b_pack(b.z, b.w) };
        ((uint4*)relb)[i] = o;
        return;
    }
    const float* W; unsigned short* WT; int N, l;
    if (bid < 4100)      { W = Wq; WT = WqT; N = 1024; l = bid - 3076; }
    else if (bid < 4356) { W = Wk; WT = WkT; N = 256;  l = bid - 4100; }
    else if (bid < 4612) { W = Wv; WT = WvT; N = 256;  l = bid - 4356; }
    else                 { W = Wo; WT = WoT; N = 1024; l = bid - 4612; }
    const int nbx = N >> 5;
    const int n0 = (l % nbx) * 32, k0 = (l / nbx) * 32;
    __shared__ float t[32][33];
    const int tx = threadIdx.x & 31, ty = threadIdx.x >> 5;
    #pragma unroll
    for (int i = 0; i < 4; i++)
        t[ty + i * 8][tx] = W[(size_t)(k0 + ty + i * 8) * N + n0 + tx];
    __syncthreads();
    #pragma unroll
    for (int i = 0; i < 4; i++)
        WT[(size_t)(n0 + ty + i * 8) * 1024 + k0 + tx] = f2b1(t[tx][ty + i * 8]);
}

// ---------- bf16 MFMA GEMM body: C[M,N] = alpha * A[M,K] @ BT[N,K]^T ----------
template<bool OUTBF16>
__device__ __forceinline__ void gemm_body(
    const unsigned short* __restrict__ A, const unsigned short* __restrict__ BT,
    void* __restrict__ Cv, int M, int N, int K, float alpha)
{
    __shared__ __attribute__((aligned(16))) unsigned short As[64 * 64];
    __shared__ __attribute__((aligned(16))) unsigned short Bs[64 * 64];
    const int tid = threadIdx.x;
    const int lane = tid & 63, wave = tid >> 6;
    const int wr = wave >> 1, wc = wave & 1;
    const int m0 = blockIdx.y * 64, n0 = blockIdx.x * 64;
    const int qn = lane & 15, lg8 = (lane >> 4) * 8;
    const int rsub = lane >> 3, cb8 = (lane & 7) * 8;

    const unsigned short* aSrc = A + (size_t)(m0 + wave * 16 + rsub) * K + cb8;
    const unsigned short* bSrc = BT + (size_t)(n0 + wave * 16 + rsub) * K + cb8;

    f32x4 acc[2][2];
    #pragma unroll
    for (int x = 0; x < 2; x++)
        #pragma unroll
        for (int y = 0; y < 2; y++)
            acc[x][y] = (f32x4){0.f, 0.f, 0.f, 0.f};

    for (int k0 = 0; k0 < K; k0 += 64) {
        #pragma unroll
        for (int i = 0; i < 2; i++)
            gload16(aSrc + (size_t)i * 8 * K + k0, &As[(wave * 2 + i) * 512]);
        #pragma unroll
        for (int i = 0; i < 2; i++)
            gload16(bSrc + (size_t)i * 8 * K + k0, &Bs[(wave * 2 + i) * 512]);
        __syncthreads();
        #pragma unroll
        for (int ks = 0; ks < 2; ks++) {
            bf16x8 af[2], bfr[2];
            #pragma unroll
            for (int x = 0; x < 2; x++)
                af[x] = *(const bf16x8*)&As[(wr * 32 + x * 16 + qn) * 64 + ks * 32 + lg8];
            #pragma unroll
            for (int y = 0; y < 2; y++)
                bfr[y] = *(const bf16x8*)&Bs[(wc * 32 + y * 16 + qn) * 64 + ks * 32 + lg8];
            #pragma unroll
            for (int x = 0; x < 2; x++)
                #pragma unroll
                for (int y = 0; y < 2; y++)
                    acc[x][y] = __builtin_amdgcn_mfma_f32_16x16x32_bf16(af[x], bfr[y], acc[x][y], 0, 0, 0);
        }
        __syncthreads();
    }
    const int r4 = (lane >> 4) * 4;
    #pragma unroll
    for (int x = 0; x < 2; x++)
        #pragma unroll
        for (int y = 0; y < 2; y++) {
            const int row = m0 + wr * 32 + x * 16 + r4;
            const int col = n0 + wc * 32 + y * 16 + qn;
            #pragma unroll
            for (int r = 0; r < 4; r++) {
                float vv = acc[x][y][r] * alpha;
                if (OUTBF16)
                    ((unsigned short*)Cv)[(size_t)(row + r) * N + col] = f2b1(vv);
                else
                    ((float*)Cv)[(size_t)(row + r) * N + col] = vv;
            }
        }
}

template<bool OUTBF16>
__global__ __launch_bounds__(256) void gemm_bt(
    const unsigned short* __restrict__ A, const unsigned short* __restrict__ BT,
    void* __restrict__ Cv, int M, int N, int K, float alpha)
{
    gemm_body<OUTBF16>(A, BT, Cv, M, N, K, alpha);
}

// ---------- merged QKV projection: per-n-block A AND C routing ----------
// BTcat = WqT|WkT|WvT (contiguous rows 0..1535).
// n0<1024: A=qb -> qh (alpha 0.125); n0<1280: A=kb -> kh; else: A=vb -> vh.
__global__ __launch_bounds__(256) void gemm_qkv(
    const unsigned short* __restrict__ qb, const unsigned short* __restrict__ kb,
    const unsigned short* __restrict__ vb, const unsigned short* __restrict__ BTcat,
    unsigned short* __restrict__ qh, unsigned short* __restrict__ kh,
    unsigned short* __restrict__ vh)
{
    __shared__ __attribute__((aligned(16))) unsigned short As[64 * 64];
    __shared__ __attribute__((aligned(16))) unsigned short Bs[64 * 64];
    const int tid = threadIdx.x;
    const int lane = tid & 63, wave = tid >> 6;
    const int wr = wave >> 1, wc = wave & 1;
    const int m0 = blockIdx.y * 64, n0 = blockIdx.x * 64;
    const int qn = lane & 15, lg8 = (lane >> 4) * 8;
    const int rsub = lane >> 3, cb8 = (lane & 7) * 8;
    const int K = 1024;

    // route A and C by n-block (uniform per block)
    const unsigned short* Abase; unsigned short* Cbase; int Nout, coff; float alpha;
    if (n0 < 1024)      { Abase = qb; Cbase = qh; Nout = 1024; coff = n0;        alpha = 0.125f; }
    else if (n0 < 1280) { Abase = kb; Cbase = kh; Nout = 256;  coff = n0 - 1024; alpha = 1.0f; }
    else                { Abase = vb; Cbase = vh; Nout = 256;  coff = n0 - 1280; alpha = 1.0f; }

    const unsigned short* aSrc = Abase + (size_t)(m0 + wave * 16 + rsub) * K + cb8;
    const unsigned short* bSrc = BTcat + (size_t)(n0 + wave * 16 + rsub) * K + cb8;

    f32x4 acc[2][2];
    #pragma unroll
    for (int x = 0; x < 2; x++)
        #pragma unroll
        for (int y = 0; y < 2; y++)
            acc[x][y] = (f32x4){0.f, 0.f, 0.f, 0.f};

    for (int k0 = 0; k0 < K; k0 += 64) {
        #pragma unroll
        for (int i = 0; i < 2; i++)
            gload16(aSrc + (size_t)i * 8 * K + k0, &As[(wave * 2 + i) * 512]);
        #pragma unroll
        for (int i = 0; i < 2; i++)
            gload16(bSrc + (size_t)i * 8 * K + k0, &Bs[(wave * 2 + i) * 512]);
        __syncthreads();
        #pragma unroll
        for (int ks = 0; ks < 2; ks++) {
            bf16x8 af[2], bfr[2];
            #pragma unroll
            for (int x = 0; x < 2; x++)
                af[x] = *(const bf16x8*)&As[(wr * 32 + x * 16 + qn) * 64 + ks * 32 + lg8];
            #pragma unroll
            for (int y = 0; y < 2; y++)
                bfr[y] = *(const bf16x8*)&Bs[(wc * 32 + y * 16 + qn) * 64 + ks * 32 + lg8];
            #pragma unroll
            for (int x = 0; x < 2; x++)
                #pragma unroll
                for (int y = 0; y < 2; y++)
                    acc[x][y] = __builtin_amdgcn_mfma_f32_16x16x32_bf16(af[x], bfr[y], acc[x][y], 0, 0, 0);
        }
        __syncthreads();
    }
    const int r4 = (lane >> 4) * 4;
    #pragma unroll
    for (int x = 0; x < 2; x++)
        #pragma unroll
        for (int y = 0; y < 2; y++) {
            const int row = m0 + wr * 32 + x * 16 + r4;
            const int col = coff + wc * 32 + y * 16 + qn;
            #pragma unroll
            for (int r = 0; r < 4; r++)
                Cbase[(size_t)(row + r) * Nout + col] = f2b1(acc[x][y][r] * alpha);
        }
}

// ---------- MFMA flash attention, KVBLK=64 + fused rel-bias tile ----------
// qt mapping balanced across dispatch halves: blocks i and i+256 (same CU under
// round-robin) get complementary qt -> every CU pair sums to 17 chunk-units.
#define K_OFF(buf)  ((buf) * 8192)                    /* [64k][64d] bf16, XOR-swizzled rows */
#define V_OFF(buf)  (16384 + (buf) * 9216)            /* V^T: [64d][32 kpair dword], stride 36 dw */
#define P_OFF(w)    (34816 + (w) * 2176)              /* per-wave P^T: [32 kpair][16 q], stride 17 dw */
#define RB_OFF      43520                             /* rb tile: [64 q][129 stride] bf16 */
#define LDS_BYTES   60032

__global__ __launch_bounds__(256, 2) void attn_mfma(
    const unsigned short* __restrict__ qh, const unsigned short* __restrict__ kh,
    const unsigned short* __restrict__ vh, const unsigned short* __restrict__ relb,
    unsigned short* __restrict__ ctx)
{
    __shared__ __align__(16) unsigned char lds[LDS_BYTES];
    const int tid  = threadIdx.x;
    const int lane = tid & 63;
    const int wave = tid >> 6;
    const int qn   = lane & 15;
    const int lg   = lane >> 4;
    const int bh = blockIdx.y;
    const int b = bh >> 4, h = bh & 15;
    const int g = h >> 2;
    // complementary qt across the two 256-block dispatch halves (load balance)
    const int qt = (bh < 16) ? (15 - (int)blockIdx.x) : (int)blockIdx.x;
    const int qw0 = qt * 64 + wave * 16;
    const int qg  = qw0 + qn;
    const int nch = qt + 1;                     // 64-key chunks

    const unsigned short* kbase = kh + (size_t)b * TSEQ * KVDIM + g * HDIM;
    const unsigned short* vbase = vh + (size_t)b * TSEQ * KVDIM + g * HDIM;

    // Q fragments: col q=qn, rows d = dh*32 + lg*8 + i
    bf16x8 qf[2];
    {
        const unsigned short* qp = qh + (size_t)(b * TSEQ + qg) * DMODEL + h * HDIM;
        qf[0] = *(const bf16x8*)(qp + lg * 8);
        qf[1] = *(const bf16x8*)(qp + 32 + lg * 8);
    }

    // ---- fused rel-bias tile: per wave rows wave*16..+15, all 128 j ----
    {
        f32x4 racc[8];
        #pragma unroll
        for (int y = 0; y < 8; y++) racc[y] = (f32x4){0.f, 0.f, 0.f, 0.f};
        #pragma unroll
        for (int ks = 0; ks < 2; ks++)
            #pragma unroll
            for (int y = 0; y < 8; y++) {
                bf16x8 bfr = *(const bf16x8*)(relb + (y * 16 + qn) * 64 + ks * 32 + lg * 8);
                racc[y] = __builtin_amdgcn_mfma_f32_16x16x32_bf16(qf[ks], bfr, racc[y], 0, 0, 0);
            }
        unsigned short* rbw = (unsigned short*)(lds + RB_OFF) + (size_t)(wave * 16 + lg * 4) * 129;
        #pragma unroll
        for (int y = 0; y < 8; y++)
            #pragma unroll
            for (int r = 0; r < 4; r++)
                rbw[r * 129 + y * 16 + qn] = f2b1(racc[y][r]);
    }

    // staging thread mapping (64 keys)
    const int sk  = tid >> 2;            // K row 0..63
    const int sd0 = (tid & 3) << 4;      // K d-start elems (0,16,32,48), 2x bf16x8 each
    const int vkp = tid >> 3;            // V kpair 0..31
    const int vd0 = (tid & 7) << 3;      // V d-start elems (0,8,..,56), 8 dwords each

    f32x4 oa0 = {0.f,0.f,0.f,0.f}, oa1 = oa0, oa2 = oa0, oa3 = oa0;
    float mReg = -1e30f, lReg = 0.f;

    // ---- prologue: stage chunk 0 ----
    {
        bf16x8 kx0 = *(const bf16x8*)(kbase + (size_t)sk * KVDIM + sd0);
        bf16x8 kx1 = *(const bf16x8*)(kbase + (size_t)sk * KVDIM + sd0 + 8);
        uint4 va = *(const uint4*)(vbase + (size_t)(2 * vkp) * KVDIM + vd0);
        uint4 vvb = *(const uint4*)(vbase + (size_t)(2 * vkp + 1) * KVDIM + vd0);
        unsigned char* kd = lds + K_OFF(0) + sk * 128;
        const int sw = (sk & 7) << 4;
        *(bf16x8*)(kd + ((sd0 * 2) ^ sw)) = kx0;
        *(bf16x8*)(kd + ((sd0 * 2 + 16) ^ sw)) = kx1;
        unsigned char* vd = lds + V_OFF(0);
        const unsigned* ua = (const unsigned*)&va;
        const unsigned* ub = (const unsigned*)&vvb;
        #pragma unroll
        for (int j = 0; j < 8; j++) {
            unsigned lo = (ua[j >> 1] >> ((j & 1) * 16)) & 0xFFFFu;
            unsigned hi = (ub[j >> 1] >> ((j & 1) * 16)) & 0xFFFFu;
            *(unsigned*)(vd + (((vd0 + j) * 36 + vkp) * 4)) = lo | (hi << 16);
        }
    }
    __syncthreads();

    // per-lane rb row (in LDS) and clamped far bias
    const unsigned short* rbl = (const unsigned short*)(lds + RB_OFF) + (size_t)(wave * 16 + qn) * 129;
    const float cb = b2f(rbl[127]);

    for (int c = 0; c < nch; c++) {
        const unsigned char* kbuf = lds + K_OFF(c & 1);
        const unsigned char* vbuf = lds + V_OFF(c & 1);
        // T14: issue next-chunk global loads early
        bf16x8 kx0, kx1; uint4 va, vvb;
        const bool stage = (c + 1 < nch);
        if (stage) {
            const int k0n = (c + 1) * 64;
            kx0 = *(const bf16x8*)(kbase + (size_t)(k0n + sk) * KVDIM + sd0);
            kx1 = *(const bf16x8*)(kbase + (size_t)(k0n + sk) * KVDIM + sd0 + 8);
            va  = *(const uint4*)(vbase + (size_t)(k0n + 2 * vkp) * KVDIM + vd0);
            vvb = *(const uint4*)(vbase + (size_t)(k0n + 2 * vkp + 1) * KVDIM + vd0);
        }
        {
            const int k0 = c * 64;
            float sa[4][4];
            const bool far = (qw0 - k0) >= 190;
            #pragma unroll
            for (int kt = 0; kt < 4; kt++)
                #pragma unroll
                for (int r = 0; r < 4; r++) {
                    if (far) { sa[kt][r] = cb; }
                    else {
                        int dist = qg - (k0 + kt * 16 + lg * 4 + r);
                        sa[kt][r] = (dist < 0) ? -1e30f : b2f(rbl[min(dist, 127)]);
                    }
                }
            f32x4 acc[4];
            #pragma unroll
            for (int kt = 0; kt < 4; kt++)
                acc[kt] = (f32x4){sa[kt][0], sa[kt][1], sa[kt][2], sa[kt][3]};
            #pragma unroll
            for (int dh = 0; dh < 2; dh++) {
                #pragma unroll
                for (int kt = 0; kt < 4; kt++) {
                    const int kr = kt * 16 + qn;
                    bf16x8 kf = *(const bf16x8*)(kbuf + kr * 128 + ((dh * 64 + lg * 16) ^ ((kr & 7) << 4)));
                    acc[kt] = __builtin_amdgcn_mfma_f32_16x16x32_bf16(kf, qf[dh], acc[kt], 0, 0, 0);
                }
            }
            #pragma unroll
            for (int kt = 0; kt < 4; kt++) {
                sa[kt][0] = acc[kt][0]; sa[kt][1] = acc[kt][1];
                sa[kt][2] = acc[kt][2]; sa[kt][3] = acc[kt][3];
            }
            float mt = -1e30f;
            #pragma unroll
            for (int kt = 0; kt < 4; kt++)
                mt = fmaxf(mt, fmaxf(fmaxf(sa[kt][0], sa[kt][1]), fmaxf(sa[kt][2], sa[kt][3])));
            mt = fmaxf(mt, __shfl_xor(mt, 16));
            mt = fmaxf(mt, __shfl_xor(mt, 32));
            if (!__all(mt <= mReg + 8.0f)) {       // defer-max (T13)
                float mn = fmaxf(mReg, mt);
                float sc = __expf(mReg - mn);
                lReg *= sc;
                oa0 *= sc; oa1 *= sc; oa2 *= sc; oa3 *= sc;
                mReg = mn;
            }
            float ls = 0.f;
            #pragma unroll
            for (int kt = 0; kt < 4; kt++)
                #pragma unroll
                for (int r = 0; r < 4; r++) {
                    float e = __expf(sa[kt][r] - mReg);   // masked -> exp(-1e30)=0
                    sa[kt][r] = e; ls += e;
                }
            ls += __shfl_xor(ls, 16);
            ls += __shfl_xor(ls, 32);
            lReg += ls;
            // P^T -> per-wave LDS, read back as B-frags
            unsigned char* pb = lds + P_OFF(wave);
            #pragma unroll
            for (int kt = 0; kt < 4; kt++)
                #pragma unroll
                for (int i = 0; i < 2; i++) {
                    unsigned dw = f2b_pack(sa[kt][2 * i], sa[kt][2 * i + 1]);
                    *(unsigned*)(pb + ((kt * 8 + lg * 2 + i) * 17 + qn) * 4) = dw;
                }
            asm volatile("s_waitcnt lgkmcnt(0)" ::: "memory");
            __builtin_amdgcn_sched_barrier(0);                  // rule #18
            union { unsigned u[4]; bf16x8 v; } pf[2];
            #pragma unroll
            for (int ks = 0; ks < 2; ks++)
                #pragma unroll
                for (int j = 0; j < 4; j++)
                    pf[ks].u[j] = *(const unsigned*)(pb + (((ks * 16 + lg * 4 + j) * 17 + qn) * 4));
            #pragma unroll
            for (int ks = 0; ks < 2; ks++) {
                bf16x8 vf0 = *(const bf16x8*)(vbuf + (((0 * 16 + qn) * 36 + ks * 16 + lg * 4) * 4));
                oa0 = __builtin_amdgcn_mfma_f32_16x16x32_bf16(vf0, pf[ks].v, oa0, 0, 0, 0);
                bf16x8 vf1 = *(const bf16x8*)(vbuf + (((1 * 16 + qn) * 36 + ks * 16 + lg * 4) * 4));
                oa1 = __builtin_amdgcn_mfma_f32_16x16x32_bf16(vf1, pf[ks].v, oa1, 0, 0, 0);
                bf16x8 vf2 = *(const bf16x8*)(vbuf + (((2 * 16 + qn) * 36 + ks * 16 + lg * 4) * 4));
                oa2 = __builtin_amdgcn_mfma_f32_16x16x32_bf16(vf2, pf[ks].v, oa2, 0, 0, 0);
                bf16x8 vf3 = *(const bf16x8*)(vbuf + (((3 * 16 + qn) * 36 + ks * 16 + lg * 4) * 4));
                oa3 = __builtin_amdgcn_mfma_f32_16x16x32_bf16(vf3, pf[ks].v, oa3, 0, 0, 0);
            }
        }
        if (stage) {
            unsigned char* kd = lds + K_OFF((c + 1) & 1) + sk * 128;
            const int sw = (sk & 7) << 4;
            *(bf16x8*)(kd + ((sd0 * 2) ^ sw)) = kx0;
            *(bf16x8*)(kd + ((sd0 * 2 + 16) ^ sw)) = kx1;
            unsigned char* vd = lds + V_OFF((c + 1) & 1);
            const unsigned* ua = (const unsigned*)&va;
            const unsigned* ub = (const unsigned*)&vvb;
            #pragma unroll
            for (int j = 0; j < 8; j++) {
                unsigned lo = (ua[j >> 1] >> ((j & 1) * 16)) & 0xFFFFu;
                unsigned hi = (ub[j >> 1] >> ((j & 1) * 16)) & 0xFFFFu;
                *(unsigned*)(vd + (((vd0 + j) * 36 + vkp) * 4)) = lo | (hi << 16);
            }
        }
        __syncthreads();
    }

    // epilogue: O^T rows d = dt*16 + lg*4 + r, col q = qn -> bf16 ctx
    const float iL = 1.0f / lReg;
    unsigned short* op = ctx + (size_t)(b * TSEQ + qg) * DMODEL + h * HDIM;
    uint2 s;
    s.x = f2b_pack(oa0[0] * iL, oa0[1] * iL); s.y = f2b_pack(oa0[2] * iL, oa0[3] * iL);
    *(uint2*)(op + 0 * 16 + lg * 4) = s;
    s.x = f2b_pack(oa1[0] * iL, oa1[1] * iL); s.y = f2b_pack(oa1[2] * iL, oa1[3] * iL);
    *(uint2*)(op + 1 * 16 + lg * 4) = s;
    s.x = f2b_pack(oa2[0] * iL, oa2[1] * iL); s.y = f2b_pack(oa2[2] * iL, oa2[3] * iL);
    *(uint2*)(op + 2 * 16 + lg * 4) = s;
    s.x = f2b_pack(oa3[0] * iL, oa3[1] * iL); s.y = f2b_pack(oa3[2] * iL, oa3[3] * iL);
    *(uint2*)(op + 3 * 16 + lg * 4) = s;
}

extern "C" void kernel_launch(void* const* d_in, const int* in_sizes, int n_in,
                              void* d_out, int out_size, void* d_ws, size_t ws_size,
                              hipStream_t stream) {
    const float* q   = (const float*)d_in[0];
    const float* k   = (const float*)d_in[1];
    const float* v   = (const float*)d_in[2];
    const float* Wq  = (const float*)d_in[3];
    const float* Wk  = (const float*)d_in[4];
    const float* Wv  = (const float*)d_in[5];
    const float* Wo  = (const float*)d_in[6];
    const float* rel = (const float*)d_in[7];
    // d_in[8] = attn_mask: exactly causal (triu k=1) -> computed analytically.
    float* out = (float*)d_out;

    // workspace (ushort units); ~19 MB total.
    // WqT/WkT/WvT contiguous -> BTcat[1536][1024] for the merged QKV GEMM.
    unsigned short* qb   = (unsigned short*)d_ws;              // 2M
    unsigned short* kb   = qb   + (size_t)2048 * 1024;         // 2M
    unsigned short* vb   = kb   + (size_t)2048 * 1024;         // 2M
    unsigned short* WqT  = vb   + (size_t)2048 * 1024;         // 1M  (BTcat rows 0-1023)
    unsigned short* WkT  = WqT  + (size_t)1024 * 1024;         // 256K (rows 1024-1279)
    unsigned short* WvT  = WkT  + (size_t)256 * 1024;          // 256K (rows 1280-1535)
    unsigned short* WoT  = WvT  + (size_t)256 * 1024;          // 1M
    unsigned short* relb = WoT  + (size_t)1024 * 1024;         // 8K
    unsigned short* qh   = relb + 8192;                        // 2M
    unsigned short* kh   = qh   + (size_t)2048 * 1024;         // 512K
    unsigned short* vh   = kh   + (size_t)2048 * 256;          // 512K
    unsigned short* ctx  = qb;   // alias: qb dead after QKV projection

    prep<<<5636, 256, 0, stream>>>(q, k, v, rel, Wq, Wk, Wv, Wo,
                                   (unsigned*)qb, (unsigned*)kb, (unsigned*)vb,
                                   (unsigned*)relb, WqT, WkT, WvT, WoT);
    gemm_qkv<<<dim3(24, 32), 256, 0, stream>>>(qb, kb, vb, WqT, qh, kh, vh);
    attn_mfma<<<dim3(16, 32), 256, 0, stream>>>(qh, kh, vh, relb, ctx);
    gemm_bt<false><<<dim3(16, 32), 256, 0, stream>>>(ctx, WoT, out, 2048, 1024, 1024, 1.0f);
}